// Round 1
// baseline (941.084 us; speedup 1.0000x reference)
//
#include <hip/hip_runtime.h>
#include <cstddef>
#include <cstdint>

constexpr int BATCH = 64;
constexpr int CH    = 256;
constexpr int NPT   = 196;
constexpr int ROWS  = BATCH * NPT;   // 12544
constexpr int BSTRIDE = CH * NPT;    // 50176
constexpr int OUTC  = 512;
constexpr int KNB   = 8;             // position 8 (9th) is never valid: k_int <= 8

__device__ __forceinline__ int src_batch(int b) {
    return (b & ~15) | ((b + 1) & 15);
}

// ---------------- qs: per-point squared norm of spatial vector ----------------
__global__ __launch_bounds__(256) void qs_kernel(const float* __restrict__ x,
                                                 float* __restrict__ qs) {
    int b = blockIdx.x;
    int m = threadIdx.x;
    if (m >= NPT) return;
    const float* xb = x + (size_t)b * BSTRIDE;
    float acc = 0.f;
    for (int c = 0; c < CH; ++c) {
        float v = xb[c * NPT + m];
        acc = fmaf(v, v, acc);
    }
    qs[b * NPT + m] = acc;
}

// ---------------- Gram: D[job] = Xq * Xk^T (196x196), job<64: x-x, else x-y ----------------
__global__ __launch_bounds__(256) void gram_kernel(const float* __restrict__ x,
                                                   float* __restrict__ D) {
    __shared__ float As[16][64];
    __shared__ float Bs[16][64];
    int job = blockIdx.z;
    int qb = (job < 64) ? job : job - 64;
    int kb = (job < 64) ? qb : src_batch(qb);
    int i0 = blockIdx.y * 64, j0 = blockIdx.x * 64;
    int t = threadIdx.x;
    int tx = t & 15, ty = t >> 4;
    const float* Mq = x + (size_t)qb * BSTRIDE;
    const float* Mk = x + (size_t)kb * BSTRIDE;
    float acc[4][4] = {};
    for (int k0 = 0; k0 < CH; k0 += 16) {
        int ii = t & 63, kcb = t >> 6;
        #pragma unroll
        for (int rep = 0; rep < 4; ++rep) {
            int kc = kcb + rep * 4;
            int ci = i0 + ii, cj = j0 + ii;
            As[kc][ii] = (ci < NPT) ? Mq[(size_t)(k0 + kc) * NPT + ci] : 0.f;
            Bs[kc][ii] = (cj < NPT) ? Mk[(size_t)(k0 + kc) * NPT + cj] : 0.f;
        }
        __syncthreads();
        #pragma unroll
        for (int kc = 0; kc < 16; ++kc) {
            float a[4], bv[4];
            #pragma unroll
            for (int s = 0; s < 4; ++s) { a[s] = As[kc][ty*4+s]; bv[s] = Bs[kc][tx*4+s]; }
            #pragma unroll
            for (int i = 0; i < 4; ++i)
                #pragma unroll
                for (int j = 0; j < 4; ++j)
                    acc[i][j] = fmaf(a[i], bv[j], acc[i][j]);
        }
        __syncthreads();
    }
    #pragma unroll
    for (int i = 0; i < 4; ++i) {
        int gi = i0 + ty * 4 + i;
        if (gi >= NPT) continue;
        #pragma unroll
        for (int j = 0; j < 4; ++j) {
            int gj = j0 + tx * 4 + j;
            if (gj < NPT)
                D[(size_t)job * (NPT * NPT) + (size_t)gi * NPT + gj] = acc[i][j];
        }
    }
}

// ---------------- top-8 selection (one wave per row), lexicographic (dist, idx) ----------------
__global__ __launch_bounds__(256) void topk_kernel(const float* __restrict__ D,
                                                   const float* __restrict__ qs,
                                                   int* __restrict__ nbr) {
    int wid = threadIdx.x >> 6;
    int lane = threadIdx.x & 63;
    int rowid = blockIdx.x * 4 + wid;        // 0..128*196-1
    int job = rowid / NPT;
    int i = rowid - job * NPT;
    int qb = (job < 64) ? job : job - 64;
    int kb = (job < 64) ? qb : src_batch(qb);
    const float* drow = D + (size_t)job * (NPT * NPT) + (size_t)i * NPT;
    float qsi = qs[qb * NPT + i];
    const float* ksr = qs + kb * NPT;
    float dist[4];
    #pragma unroll
    for (int s = 0; s < 4; ++s) {
        int m = lane + 64 * s;
        dist[s] = (m < NPT) ? (qsi - 2.f * drow[m] + ksr[m])
                            : __uint_as_float(0x7f800000u);
    }
    for (int it = 0; it < KNB; ++it) {
        unsigned long long best = ~0ull;
        #pragma unroll
        for (int s = 0; s < 4; ++s) {
            unsigned u = __float_as_uint(dist[s]);
            u = (u & 0x80000000u) ? ~u : (u | 0x80000000u);
            unsigned long long key = ((unsigned long long)u << 32) |
                                     (unsigned)(lane + 64 * s);
            if (key < best) best = key;
        }
        #pragma unroll
        for (int off = 32; off; off >>= 1) {
            unsigned long long o = __shfl_xor(best, off, 64);
            if (o < best) best = o;
        }
        int widx = (int)(best & 0xffffffffu);
        if (lane == (widx & 63)) dist[widx >> 6] = __uint_as_float(0x7f800000u);
        if (lane == 0) nbr[(size_t)rowid * KNB + it] = widx;
    }
}

// ---------------- fused k-predictor MLP: 256->500->64->32->9 -> argmax ----------------
__global__ __launch_bounds__(256) void kint_kernel(const float* __restrict__ x,
    const float* __restrict__ kp_w, const float* __restrict__ kp_b,
    const float* __restrict__ enc_w, const float* __restrict__ enc_b,
    const float* __restrict__ mu_w, const float* __restrict__ mu_b,
    const float* __restrict__ dec_w, const float* __restrict__ dec_b,
    int* __restrict__ kint, float* __restrict__ degf) {
    __shared__ float xr[8][256];
    __shared__ float hk[8][500];
    __shared__ float part[4][8][64];
    __shared__ float ebuf[8][64];
    __shared__ float mubuf[8][32];
    __shared__ float lg[8][9];
    int t = threadIdx.x;
    int r0 = blockIdx.x * 8;
    #pragma unroll
    for (int rr = 0; rr < 8; ++rr) xr[rr][t] = x[(size_t)(r0 + rr) * 256 + t];
    __syncthreads();
    #pragma unroll
    for (int rep = 0; rep < 2; ++rep) {
        int col = t + rep * 256;
        if (col < 500) {
            float acc[8] = {};
            for (int c = 0; c < 256; ++c) {
                float w = kp_w[(size_t)c * 500 + col];
                #pragma unroll
                for (int rr = 0; rr < 8; ++rr) acc[rr] = fmaf(xr[rr][c], w, acc[rr]);
            }
            float bv = kp_b[col];
            #pragma unroll
            for (int rr = 0; rr < 8; ++rr) hk[rr][col] = acc[rr] + bv;
        }
    }
    __syncthreads();
    {
        int col = t & 63, p = t >> 6;
        float acc[8] = {};
        for (int j = p * 125; j < p * 125 + 125; ++j) {
            float w = enc_w[(size_t)j * 64 + col];
            #pragma unroll
            for (int rr = 0; rr < 8; ++rr) acc[rr] = fmaf(hk[rr][j], w, acc[rr]);
        }
        #pragma unroll
        for (int rr = 0; rr < 8; ++rr) part[p][rr][col] = acc[rr];
    }
    __syncthreads();
    #pragma unroll
    for (int rep = 0; rep < 2; ++rep) {
        int idx = t + rep * 256;
        int rr = idx >> 6, col = idx & 63;
        float v = part[0][rr][col] + part[1][rr][col] + part[2][rr][col] +
                  part[3][rr][col] + enc_b[col];
        ebuf[rr][col] = fmaxf(v, 0.f);
    }
    __syncthreads();
    {
        int rr = t >> 5, col = t & 31;
        float acc = 0.f;
        for (int j = 0; j < 64; ++j)
            acc = fmaf(ebuf[rr][j], mu_w[(size_t)j * 32 + col], acc);
        mubuf[rr][col] = acc + mu_b[col];
    }
    __syncthreads();
    if (t < 72) {
        int rr = t / 9, col = t - rr * 9;
        float acc = 0.f;
        for (int j = 0; j < 32; ++j)
            acc = fmaf(mubuf[rr][j], dec_w[(size_t)j * 9 + col], acc);
        lg[rr][col] = acc + dec_b[col];
    }
    __syncthreads();
    if (t < 8) {
        float best = lg[t][0];
        int bi = 0;
        #pragma unroll
        for (int j = 1; j < 9; ++j)
            if (lg[t][j] > best) { best = lg[t][j]; bi = j; }
        kint[r0 + t] = bi;
        degf[r0 + t] = (float)bi;
    }
}

// ---------------- gather: Z = [deg*feat | nbr_sum - deg*feat] ----------------
template<int REMAP>
__global__ __launch_bounds__(256) void gather_kernel(const float* __restrict__ feat,
        const int* __restrict__ nbr, const int* __restrict__ kint,
        const float* __restrict__ degf, float* __restrict__ Z) {
    int g = threadIdx.x >> 6, lane = threadIdx.x & 63;
    int r = blockIdx.x * 4 + g;
    int b = r / NPT, i = r - b * NPT;
    int fb = REMAP ? src_batch(b) : b;
    const float4* self4 = (const float4*)(feat + ((size_t)fb * NPT + i) * CH);
    float4 sv = self4[lane];
    float dg = degf[r];
    int kk = kint[r];
    const int* nb = nbr + (size_t)r * KNB;
    float4 s = make_float4(0.f, 0.f, 0.f, 0.f);
    for (int t = 0; t < kk; ++t) {
        int m = nb[t];
        const float4* n4 = (const float4*)(feat + ((size_t)fb * NPT + m) * CH);
        float4 v = n4[lane];
        s.x += v.x; s.y += v.y; s.z += v.z; s.w += v.w;
    }
    float4 a = make_float4(dg * sv.x, dg * sv.y, dg * sv.z, dg * sv.w);
    float4 d = make_float4(s.x - a.x, s.y - a.y, s.z - a.z, s.w - a.w);
    float4* z0 = (float4*)(Z + (size_t)r * 512);
    z0[lane] = a;
    z0[lane + 64] = d;
}

// ---------------- generic f32 GEMM: C = op(A @ W + bias) ----------------
// AMODE 0: plain A (ROWS x Kd). AMODE 1: A cols<512 from A(=xin), cols>=512 wgt-mix of xagg/yagg.
// OMODE 0: C row-major (ROWS x N).  OMODE 1: transposed final write out[b][c][i].
template<int RELU, int DEGB, int AMODE, int OMODE>
__global__ __launch_bounds__(256) void gemm_kernel(
    const float* __restrict__ A, const float* __restrict__ W,
    const float* __restrict__ bias, float* __restrict__ C,
    int Kd, int N,
    const float* __restrict__ degf,
    const float* __restrict__ xagg, const float* __restrict__ yagg,
    const float* __restrict__ wgt) {
    __shared__ float As[16][68];
    __shared__ float Bs[16][64];
    int t = threadIdx.x;
    int tx = t & 15, ty = t >> 4;
    int c0 = blockIdx.x * 64;
    int r0 = blockIdx.y * 64;
    float acc[4][4] = {};
    for (int k0 = 0; k0 < Kd; k0 += 16) {
        {
            int iib = t >> 4, kc = t & 15;
            int kk = k0 + kc;
            #pragma unroll
            for (int rep = 0; rep < 4; ++rep) {
                int ii = iib + rep * 16;
                int r = r0 + ii;
                float v;
                if constexpr (AMODE == 0) {
                    v = A[(size_t)r * Kd + kk];
                } else {
                    if (kk < 512) {
                        v = A[(size_t)r * 512 + kk];
                    } else {
                        float wv = wgt[r];
                        int cc = kk - 512;
                        v = wv * xagg[(size_t)r * 512 + cc] +
                            (1.f - wv) * yagg[(size_t)r * 512 + cc];
                    }
                }
                As[kc][ii] = v;
            }
            int jj = t & 63, kcb = t >> 6;
            #pragma unroll
            for (int rep = 0; rep < 4; ++rep) {
                int kc2 = kcb + rep * 4;
                Bs[kc2][jj] = W[(size_t)(k0 + kc2) * N + c0 + jj];
            }
        }
        __syncthreads();
        #pragma unroll
        for (int kc = 0; kc < 16; ++kc) {
            float a[4], bv[4];
            #pragma unroll
            for (int s = 0; s < 4; ++s) a[s] = As[kc][ty * 4 + s];
            #pragma unroll
            for (int s = 0; s < 4; ++s) bv[s] = Bs[kc][tx * 4 + s];
            #pragma unroll
            for (int i = 0; i < 4; ++i)
                #pragma unroll
                for (int j = 0; j < 4; ++j)
                    acc[i][j] = fmaf(a[i], bv[j], acc[i][j]);
        }
        __syncthreads();
    }
    if constexpr (OMODE == 0) {
        #pragma unroll
        for (int i = 0; i < 4; ++i) {
            int r = r0 + ty * 4 + i;
            float dsc = DEGB ? degf[r] : 1.f;
            float4 o;
            o.x = acc[i][0] + dsc * bias[c0 + tx * 4 + 0];
            o.y = acc[i][1] + dsc * bias[c0 + tx * 4 + 1];
            o.z = acc[i][2] + dsc * bias[c0 + tx * 4 + 2];
            o.w = acc[i][3] + dsc * bias[c0 + tx * 4 + 3];
            if (RELU) {
                o.x = fmaxf(o.x, 0.f); o.y = fmaxf(o.y, 0.f);
                o.z = fmaxf(o.z, 0.f); o.w = fmaxf(o.w, 0.f);
            }
            *(float4*)(C + (size_t)r * N + c0 + tx * 4) = o;
        }
    } else {
        #pragma unroll
        for (int i = 0; i < 4; ++i) {
            int r = r0 + ty * 4 + i;
            int bb = r / NPT, ii = r - bb * NPT;
            #pragma unroll
            for (int j = 0; j < 4; ++j) {
                int c = c0 + tx * 4 + j;
                float v = acc[i][j] + bias[c];
                if (RELU) v = fmaxf(v, 0.f);
                C[((size_t)bb * OUTC + c) * NPT + ii] = v;
            }
        }
    }
}

// ---------------- attention scores ----------------
__global__ __launch_bounds__(256) void scores_kernel(const float* __restrict__ xagg,
        const float* __restrict__ yagg, const float* __restrict__ aw,
        const float* __restrict__ ab, float* __restrict__ scores) {
    int g = threadIdx.x >> 6, lane = threadIdx.x & 63;
    int r = blockIdx.x * 4 + g;
    float acc = 0.f;
    #pragma unroll
    for (int s = 0; s < 8; ++s) {
        int c = lane + 64 * s;
        acc = fmaf(xagg[(size_t)r * 512 + c], aw[c], acc);
        acc = fmaf(yagg[(size_t)r * 512 + c], aw[512 + c], acc);
    }
    #pragma unroll
    for (int off = 32; off; off >>= 1) acc += __shfl_xor(acc, off, 64);
    if (lane == 0) scores[r] = acc + ab[0];
}

// ---------------- global softmax over 12544 scores -> wgt ----------------
__global__ __launch_bounds__(1024) void softmax_kernel(const float* __restrict__ scores,
                                                       float* __restrict__ wgt) {
    __shared__ float red[1024];
    int t = threadIdx.x;
    float mx = -3.402823466e+38f;
    for (int i = t; i < ROWS; i += 1024) mx = fmaxf(mx, scores[i]);
    red[t] = mx; __syncthreads();
    for (int off = 512; off; off >>= 1) {
        if (t < off) red[t] = fmaxf(red[t], red[t + off]);
        __syncthreads();
    }
    mx = red[0]; __syncthreads();
    float sm = 0.f;
    for (int i = t; i < ROWS; i += 1024) sm += expf(scores[i] - mx);
    red[t] = sm; __syncthreads();
    for (int off = 512; off; off >>= 1) {
        if (t < off) red[t] += red[t + off];
        __syncthreads();
    }
    float denom = red[0];
    for (int i = t; i < ROWS; i += 1024) wgt[i] = expf(scores[i] - mx) / denom;
}

extern "C" void kernel_launch(void* const* d_in, const int* in_sizes, int n_in,
                              void* d_out, int out_size, void* d_ws, size_t ws_size,
                              hipStream_t stream) {
    (void)in_sizes; (void)n_in; (void)out_size; (void)ws_size;
    const float* x       = (const float*)d_in[0];
    const float* fc1_w   = (const float*)d_in[1];
    const float* fc1_b   = (const float*)d_in[2];
    const float* fc2_w   = (const float*)d_in[3];
    const float* fc2_b   = (const float*)d_in[4];
    const float* fce_w   = (const float*)d_in[5];
    const float* fce_b   = (const float*)d_in[6];
    const float* inout_w = (const float*)d_in[7];
    const float* inout_b = (const float*)d_in[8];
    const float* attn_w  = (const float*)d_in[9];
    const float* attn_b  = (const float*)d_in[10];
    const float* upd_w   = (const float*)d_in[11];
    const float* upd_b   = (const float*)d_in[12];
    const float* kp_w    = (const float*)d_in[13];
    const float* kp_b    = (const float*)d_in[14];
    const float* enc_w   = (const float*)d_in[15];
    const float* enc_b   = (const float*)d_in[16];
    const float* mu_w    = (const float*)d_in[17];
    const float* mu_b    = (const float*)d_in[18];
    const float* dec_w   = (const float*)d_in[19];
    const float* dec_b   = (const float*)d_in[20];
    float* out = (float*)d_out;

    float* ws = (float*)d_ws;
    size_t o = 0;
    float* qs     = ws + o; o += ROWS;
    float* degf   = ws + o; o += ROWS;
    float* scores = ws + o; o += ROWS;
    float* wgt    = ws + o; o += ROWS;
    int*   kint   = (int*)(ws + o); o += ROWS;
    float* D      = ws + o; o += (size_t)128 * NPT * NPT;
    int*   nbr    = (int*)(ws + o); o += (size_t)128 * NPT * KNB;
    float* Z      = ws + o; o += (size_t)ROWS * 512;
    float* H1     = ws + o; o += (size_t)ROWS * 256;
    float* H2     = ws + o; o += (size_t)ROWS * 256;
    float* XAGG   = ws + o; o += (size_t)ROWS * 512;
    float* YAGG   = ws + o; o += (size_t)ROWS * 512;
    float* XIN    = ws + o; o += (size_t)ROWS * 512;

    const int* nbrx = nbr;
    const int* nbry = nbr + (size_t)64 * NPT * KNB;

    qs_kernel<<<64, 256, 0, stream>>>(x, qs);
    gram_kernel<<<dim3(4, 4, 128), 256, 0, stream>>>(x, D);
    topk_kernel<<<(128 * NPT) / 4, 256, 0, stream>>>(D, qs, nbr);
    kint_kernel<<<ROWS / 8, 256, 0, stream>>>(x, kp_w, kp_b, enc_w, enc_b,
                                              mu_w, mu_b, dec_w, dec_b, kint, degf);

    // ---- x branch ----
    gather_kernel<0><<<ROWS / 4, 256, 0, stream>>>(x, nbrx, kint, degf, Z);
    gemm_kernel<1, 1, 0, 0><<<dim3(4, 196), 256, 0, stream>>>(
        Z, fc1_w, fc1_b, H1, 512, 256, degf, nullptr, nullptr, nullptr);
    gather_kernel<0><<<ROWS / 4, 256, 0, stream>>>(H1, nbrx, kint, degf, Z);
    gemm_kernel<0, 1, 0, 0><<<dim3(4, 196), 256, 0, stream>>>(
        Z, fc2_w, fc2_b, H2, 512, 256, degf, nullptr, nullptr, nullptr);
    gemm_kernel<0, 0, 0, 0><<<dim3(8, 196), 256, 0, stream>>>(
        H2, fce_w, fce_b, XAGG, 256, 512, nullptr, nullptr, nullptr, nullptr);

    // ---- y branch (features are x_feat of src batch for stage 1) ----
    gather_kernel<1><<<ROWS / 4, 256, 0, stream>>>(x, nbry, kint, degf, Z);
    gemm_kernel<1, 1, 0, 0><<<dim3(4, 196), 256, 0, stream>>>(
        Z, fc1_w, fc1_b, H1, 512, 256, degf, nullptr, nullptr, nullptr);
    gather_kernel<0><<<ROWS / 4, 256, 0, stream>>>(H1, nbry, kint, degf, Z);
    gemm_kernel<0, 1, 0, 0><<<dim3(4, 196), 256, 0, stream>>>(
        Z, fc2_w, fc2_b, H2, 512, 256, degf, nullptr, nullptr, nullptr);
    gemm_kernel<0, 0, 0, 0><<<dim3(8, 196), 256, 0, stream>>>(
        H2, fce_w, fce_b, YAGG, 256, 512, nullptr, nullptr, nullptr, nullptr);

    // ---- attention fusion ----
    scores_kernel<<<ROWS / 4, 256, 0, stream>>>(XAGG, YAGG, attn_w, attn_b, scores);
    softmax_kernel<<<1, 1024, 0, stream>>>(scores, wgt);

    // ---- xin + final update GEMM (writes transposed output) ----
    gemm_kernel<0, 0, 0, 0><<<dim3(8, 196), 256, 0, stream>>>(
        x, inout_w, inout_b, XIN, 256, 512, nullptr, nullptr, nullptr, nullptr);
    gemm_kernel<1, 0, 1, 1><<<dim3(8, 196), 256, 0, stream>>>(
        XIN, upd_w, upd_b, out, 1024, 512, nullptr, XAGG, YAGG, wgt);
}

// Round 2
// 444.505 us; speedup vs baseline: 2.1172x; 2.1172x over previous
//
#include <hip/hip_runtime.h>
#include <cstddef>
#include <cstdint>

constexpr int BATCH = 64;
constexpr int CH    = 256;
constexpr int NPT   = 196;
constexpr int ROWS  = BATCH * NPT;   // 12544
constexpr int BSTRIDE = CH * NPT;    // 50176
constexpr int KNB   = 8;             // position 8 (9th) is never valid: k_int <= 8

typedef __bf16 bf16x8 __attribute__((ext_vector_type(8)));
typedef __bf16 bf16x4 __attribute__((ext_vector_type(4)));
typedef float  f32x4  __attribute__((ext_vector_type(4)));

__device__ __forceinline__ int src_batch(int b) {
    return (b & ~15) | ((b + 1) & 15);
}

__device__ __forceinline__ void gload_lds16(const void* g, void* l) {
    __builtin_amdgcn_global_load_lds(
        (const __attribute__((address_space(1))) void*)g,
        (__attribute__((address_space(3))) void*)l, 16, 0, 0);
}

// ---------------- qs: per-point squared norm (unchanged, f32-exact) ----------------
__global__ __launch_bounds__(256) void qs_kernel(const float* __restrict__ x,
                                                 float* __restrict__ qs) {
    int b = blockIdx.x;
    int m = threadIdx.x;
    if (m >= NPT) return;
    const float* xb = x + (size_t)b * BSTRIDE;
    float acc = 0.f;
    for (int c = 0; c < CH; ++c) {
        float v = xb[c * NPT + m];
        acc = fmaf(v, v, acc);
    }
    qs[b * NPT + m] = acc;
}

// ---------------- Gram (unchanged, f32-exact for KNN determinism) ----------------
__global__ __launch_bounds__(256) void gram_kernel(const float* __restrict__ x,
                                                   float* __restrict__ D) {
    __shared__ float As[16][64];
    __shared__ float Bs[16][64];
    int job = blockIdx.z;
    int qb = (job < 64) ? job : job - 64;
    int kb = (job < 64) ? qb : src_batch(qb);
    int i0 = blockIdx.y * 64, j0 = blockIdx.x * 64;
    int t = threadIdx.x;
    int tx = t & 15, ty = t >> 4;
    const float* Mq = x + (size_t)qb * BSTRIDE;
    const float* Mk = x + (size_t)kb * BSTRIDE;
    float acc[4][4] = {};
    for (int k0 = 0; k0 < CH; k0 += 16) {
        int ii = t & 63, kcb = t >> 6;
        #pragma unroll
        for (int rep = 0; rep < 4; ++rep) {
            int kc = kcb + rep * 4;
            int ci = i0 + ii, cj = j0 + ii;
            As[kc][ii] = (ci < NPT) ? Mq[(size_t)(k0 + kc) * NPT + ci] : 0.f;
            Bs[kc][ii] = (cj < NPT) ? Mk[(size_t)(k0 + kc) * NPT + cj] : 0.f;
        }
        __syncthreads();
        #pragma unroll
        for (int kc = 0; kc < 16; ++kc) {
            float a[4], bv[4];
            #pragma unroll
            for (int s = 0; s < 4; ++s) { a[s] = As[kc][ty*4+s]; bv[s] = Bs[kc][tx*4+s]; }
            #pragma unroll
            for (int i = 0; i < 4; ++i)
                #pragma unroll
                for (int j = 0; j < 4; ++j)
                    acc[i][j] = fmaf(a[i], bv[j], acc[i][j]);
        }
        __syncthreads();
    }
    #pragma unroll
    for (int i = 0; i < 4; ++i) {
        int gi = i0 + ty * 4 + i;
        if (gi >= NPT) continue;
        #pragma unroll
        for (int j = 0; j < 4; ++j) {
            int gj = j0 + tx * 4 + j;
            if (gj < NPT)
                D[(size_t)job * (NPT * NPT) + (size_t)gi * NPT + gj] = acc[i][j];
        }
    }
}

// ---------------- top-8 selection (unchanged) ----------------
__global__ __launch_bounds__(256) void topk_kernel(const float* __restrict__ D,
                                                   const float* __restrict__ qs,
                                                   int* __restrict__ nbr) {
    int wid = threadIdx.x >> 6;
    int lane = threadIdx.x & 63;
    int rowid = blockIdx.x * 4 + wid;
    int job = rowid / NPT;
    int i = rowid - job * NPT;
    int qb = (job < 64) ? job : job - 64;
    int kb = (job < 64) ? qb : src_batch(qb);
    const float* drow = D + (size_t)job * (NPT * NPT) + (size_t)i * NPT;
    float qsi = qs[qb * NPT + i];
    const float* ksr = qs + kb * NPT;
    float dist[4];
    #pragma unroll
    for (int s = 0; s < 4; ++s) {
        int m = lane + 64 * s;
        dist[s] = (m < NPT) ? (qsi - 2.f * drow[m] + ksr[m])
                            : __uint_as_float(0x7f800000u);
    }
    for (int it = 0; it < KNB; ++it) {
        unsigned long long best = ~0ull;
        #pragma unroll
        for (int s = 0; s < 4; ++s) {
            unsigned u = __float_as_uint(dist[s]);
            u = (u & 0x80000000u) ? ~u : (u | 0x80000000u);
            unsigned long long key = ((unsigned long long)u << 32) |
                                     (unsigned)(lane + 64 * s);
            if (key < best) best = key;
        }
        #pragma unroll
        for (int off = 32; off; off >>= 1) {
            unsigned long long o = __shfl_xor(best, off, 64);
            if (o < best) best = o;
        }
        int widx = (int)(best & 0xffffffffu);
        if (lane == (widx & 63)) dist[widx >> 6] = __uint_as_float(0x7f800000u);
        if (lane == 0) nbr[(size_t)rowid * KNB + it] = widx;
    }
}

// ---------------- k-predictor MLP (unchanged, f32-exact for argmax) ----------------
__global__ __launch_bounds__(256) void kint_kernel(const float* __restrict__ x,
    const float* __restrict__ kp_w, const float* __restrict__ kp_b,
    const float* __restrict__ enc_w, const float* __restrict__ enc_b,
    const float* __restrict__ mu_w, const float* __restrict__ mu_b,
    const float* __restrict__ dec_w, const float* __restrict__ dec_b,
    int* __restrict__ kint, float* __restrict__ degf) {
    __shared__ float xr[8][256];
    __shared__ float hk[8][500];
    __shared__ float part[4][8][64];
    __shared__ float ebuf[8][64];
    __shared__ float mubuf[8][32];
    __shared__ float lg[8][9];
    int t = threadIdx.x;
    int r0 = blockIdx.x * 8;
    #pragma unroll
    for (int rr = 0; rr < 8; ++rr) xr[rr][t] = x[(size_t)(r0 + rr) * 256 + t];
    __syncthreads();
    #pragma unroll
    for (int rep = 0; rep < 2; ++rep) {
        int col = t + rep * 256;
        if (col < 500) {
            float acc[8] = {};
            for (int c = 0; c < 256; ++c) {
                float w = kp_w[(size_t)c * 500 + col];
                #pragma unroll
                for (int rr = 0; rr < 8; ++rr) acc[rr] = fmaf(xr[rr][c], w, acc[rr]);
            }
            float bv = kp_b[col];
            #pragma unroll
            for (int rr = 0; rr < 8; ++rr) hk[rr][col] = acc[rr] + bv;
        }
    }
    __syncthreads();
    {
        int col = t & 63, p = t >> 6;
        float acc[8] = {};
        for (int j = p * 125; j < p * 125 + 125; ++j) {
            float w = enc_w[(size_t)j * 64 + col];
            #pragma unroll
            for (int rr = 0; rr < 8; ++rr) acc[rr] = fmaf(hk[rr][j], w, acc[rr]);
        }
        #pragma unroll
        for (int rr = 0; rr < 8; ++rr) part[p][rr][col] = acc[rr];
    }
    __syncthreads();
    #pragma unroll
    for (int rep = 0; rep < 2; ++rep) {
        int idx = t + rep * 256;
        int rr = idx >> 6, col = idx & 63;
        float v = part[0][rr][col] + part[1][rr][col] + part[2][rr][col] +
                  part[3][rr][col] + enc_b[col];
        ebuf[rr][col] = fmaxf(v, 0.f);
    }
    __syncthreads();
    {
        int rr = t >> 5, col = t & 31;
        float acc = 0.f;
        for (int j = 0; j < 64; ++j)
            acc = fmaf(ebuf[rr][j], mu_w[(size_t)j * 32 + col], acc);
        mubuf[rr][col] = acc + mu_b[col];
    }
    __syncthreads();
    if (t < 72) {
        int rr = t / 9, col = t - rr * 9;
        float acc = 0.f;
        for (int j = 0; j < 32; ++j)
            acc = fmaf(mubuf[rr][j], dec_w[(size_t)j * 9 + col], acc);
        lg[rr][col] = acc + dec_b[col];
    }
    __syncthreads();
    if (t < 8) {
        float best = lg[t][0];
        int bi = 0;
        #pragma unroll
        for (int j = 1; j < 9; ++j)
            if (lg[t][j] > best) { best = lg[t][j]; bi = j; }
        kint[r0 + t] = bi;
        degf[r0 + t] = (float)bi;
    }
}

// ---------------- gather: Z(bf16) = [deg*feat | nbr_sum - deg*feat] ----------------
template<int REMAP, int BF16IN>
__global__ __launch_bounds__(256) void gather_kernel(const void* __restrict__ featv,
        const int* __restrict__ nbr, const int* __restrict__ kint_,
        const float* __restrict__ degf, __bf16* __restrict__ Z) {
    int g = threadIdx.x >> 6, lane = threadIdx.x & 63;
    int r = blockIdx.x * 4 + g;
    int b = r / NPT, i = r - b * NPT;
    int fb = REMAP ? src_batch(b) : b;
    float sv[4];
    if constexpr (BF16IN) {
        const __bf16* feat = (const __bf16*)featv;
        bf16x4 v = *(const bf16x4*)(feat + ((size_t)fb * NPT + i) * CH + lane * 4);
        #pragma unroll
        for (int j = 0; j < 4; ++j) sv[j] = (float)v[j];
    } else {
        const float* feat = (const float*)featv;
        float4 v = *(const float4*)(feat + ((size_t)fb * NPT + i) * CH + lane * 4);
        sv[0] = v.x; sv[1] = v.y; sv[2] = v.z; sv[3] = v.w;
    }
    float s[4] = {0.f, 0.f, 0.f, 0.f};
    int kk = kint_[r];
    const int* nb = nbr + (size_t)r * KNB;
    for (int tt = 0; tt < kk; ++tt) {
        int m = nb[tt];
        if constexpr (BF16IN) {
            const __bf16* feat = (const __bf16*)featv;
            bf16x4 v = *(const bf16x4*)(feat + ((size_t)fb * NPT + m) * CH + lane * 4);
            #pragma unroll
            for (int j = 0; j < 4; ++j) s[j] += (float)v[j];
        } else {
            const float* feat = (const float*)featv;
            float4 v = *(const float4*)(feat + ((size_t)fb * NPT + m) * CH + lane * 4);
            s[0] += v.x; s[1] += v.y; s[2] += v.z; s[3] += v.w;
        }
    }
    float dg = degf[r];
    bf16x4 av, dv;
    #pragma unroll
    for (int j = 0; j < 4; ++j) {
        float a = dg * sv[j];
        av[j] = (__bf16)a;
        dv[j] = (__bf16)(s[j] - a);
    }
    *(bf16x4*)(Z + (size_t)r * 512 + lane * 4) = av;
    *(bf16x4*)(Z + (size_t)r * 512 + 256 + lane * 4) = dv;
}

// ---------------- bf16 MFMA GEMM: C = op(A @ W + [deg*]bias) ----------------
// FLAGS: 1=RELU, 2=DEG-scaled bias, 4=bf16 output (else f32).
// CONCAT: A row = [A0 row (512) | A1 row (512)], K=1024.
// BM=BN=128, BK=64, 4 waves (2x2), each wave 64x64 via 4x4 x 16x16x32 MFMA.
template<int FLAGS, int CONCAT>
__global__ __launch_bounds__(256) void mfma_gemm(
    const __bf16* __restrict__ A0, const __bf16* __restrict__ A1,
    const __bf16* __restrict__ WT, const float* __restrict__ bias,
    const float* __restrict__ degf, float* __restrict__ Cf,
    __bf16* __restrict__ Cb, int K, int N) {
    __shared__ __attribute__((aligned(16))) __bf16 As[128 * 64];
    __shared__ __attribute__((aligned(16))) __bf16 Bs[128 * 64];
    int t = threadIdx.x, w = t >> 6, l = t & 63;
    int r0 = blockIdx.y * 128, c0 = blockIdx.x * 128;
    int lr = l & 15, lg = l >> 4;
    int wr = (w >> 1) * 64, wc = (w & 1) * 64;
    f32x4 acc[4][4] = {};
    for (int k0 = 0; k0 < K; k0 += 64) {
        const __bf16* Ab = A0;
        int kk = k0;
        size_t KA = CONCAT ? 512 : (size_t)K;
        if (CONCAT && k0 >= 512) { Ab = A1; kk = k0 - 512; }
        #pragma unroll
        for (int i = 0; i < 4; ++i) {
            int row = (w * 4 + i) * 8 + (l >> 3);
            int c8 = l & 7;
            gload_lds16(Ab + (size_t)(r0 + row) * KA + kk + c8 * 8,
                        As + (w * 4 + i) * 512);
            gload_lds16(WT + (size_t)(c0 + row) * K + k0 + c8 * 8,
                        Bs + (w * 4 + i) * 512);
        }
        asm volatile("s_waitcnt vmcnt(0)" ::: "memory");
        __syncthreads();
        #pragma unroll
        for (int ks = 0; ks < 2; ++ks) {
            bf16x8 af[4], bfr[4];
            #pragma unroll
            for (int mi = 0; mi < 4; ++mi)
                af[mi] = *(const bf16x8*)(As + (wr + mi * 16 + lr) * 64 + ks * 32 + lg * 8);
            #pragma unroll
            for (int ni = 0; ni < 4; ++ni)
                bfr[ni] = *(const bf16x8*)(Bs + (wc + ni * 16 + lr) * 64 + ks * 32 + lg * 8);
            #pragma unroll
            for (int mi = 0; mi < 4; ++mi)
                #pragma unroll
                for (int ni = 0; ni < 4; ++ni)
                    acc[mi][ni] = __builtin_amdgcn_mfma_f32_16x16x32_bf16(
                        af[mi], bfr[ni], acc[mi][ni], 0, 0, 0);
        }
        __syncthreads();
    }
    #pragma unroll
    for (int mi = 0; mi < 4; ++mi) {
        #pragma unroll
        for (int r = 0; r < 4; ++r) {
            int row = r0 + wr + mi * 16 + lg * 4 + r;
            float dsc = 1.f;
            if constexpr ((FLAGS & 2) != 0) dsc = degf[row];
            #pragma unroll
            for (int ni = 0; ni < 4; ++ni) {
                int col = c0 + wc + ni * 16 + lr;
                float v = acc[mi][ni][r] + dsc * bias[col];
                if constexpr ((FLAGS & 1) != 0) v = fmaxf(v, 0.f);
                if constexpr ((FLAGS & 4) != 0)
                    Cb[(size_t)row * N + col] = (__bf16)v;
                else
                    Cf[(size_t)row * N + col] = v;
            }
        }
    }
}

// ---------------- weight transpose + f32->bf16: WT[n][k] = W[k][n] ----------------
__global__ __launch_bounds__(256) void transpose_w(const float* __restrict__ W,
        __bf16* __restrict__ WT, int K, int N) {
    __shared__ float tile[64][65];
    int k0 = blockIdx.x * 64, n0 = blockIdx.y * 64;
    int t = threadIdx.x;
    #pragma unroll
    for (int s = 0; s < 16; ++s) {
        int idx = s * 256 + t;
        int kk = idx >> 6, nn = idx & 63;
        tile[kk][nn] = W[(size_t)(k0 + kk) * N + n0 + nn];
    }
    __syncthreads();
    #pragma unroll
    for (int s = 0; s < 16; ++s) {
        int idx = s * 256 + t;
        int nn = idx >> 6, kk = idx & 63;
        WT[(size_t)(n0 + nn) * K + k0 + kk] = (__bf16)tile[kk][nn];
    }
}

// ---------------- flat f32 -> bf16 ----------------
__global__ __launch_bounds__(256) void convert_bf16(const float* __restrict__ src,
                                                    __bf16* __restrict__ dst) {
    int idx = blockIdx.x * 256 + threadIdx.x;
    float4 v = *(const float4*)(src + (size_t)idx * 4);
    bf16x4 o;
    o[0] = (__bf16)v.x; o[1] = (__bf16)v.y; o[2] = (__bf16)v.z; o[3] = (__bf16)v.w;
    *(bf16x4*)(dst + (size_t)idx * 4) = o;
}

// ---------------- fused mix: FUSED(bf16) = wgt*XAGG + (1-wgt)*YAGG ----------------
__global__ __launch_bounds__(256) void fuse_mix(const float* __restrict__ XA,
        const float* __restrict__ YA, const float* __restrict__ wgt,
        __bf16* __restrict__ F) {
    int idx = blockIdx.x * 256 + threadIdx.x;
    size_t e0 = (size_t)idx * 4;
    int r = (int)(e0 >> 9);
    float wv = wgt[r];
    float4 xv = *(const float4*)(XA + e0);
    float4 yv = *(const float4*)(YA + e0);
    bf16x4 o;
    o[0] = (__bf16)(wv * xv.x + (1.f - wv) * yv.x);
    o[1] = (__bf16)(wv * xv.y + (1.f - wv) * yv.y);
    o[2] = (__bf16)(wv * xv.z + (1.f - wv) * yv.z);
    o[3] = (__bf16)(wv * xv.w + (1.f - wv) * yv.w);
    *(bf16x4*)(F + e0) = o;
}

// ---------------- attention scores (unchanged, f32) ----------------
__global__ __launch_bounds__(256) void scores_kernel(const float* __restrict__ xagg,
        const float* __restrict__ yagg, const float* __restrict__ aw,
        const float* __restrict__ ab, float* __restrict__ scores) {
    int g = threadIdx.x >> 6, lane = threadIdx.x & 63;
    int r = blockIdx.x * 4 + g;
    float acc = 0.f;
    #pragma unroll
    for (int s = 0; s < 8; ++s) {
        int c = lane + 64 * s;
        acc = fmaf(xagg[(size_t)r * 512 + c], aw[c], acc);
        acc = fmaf(yagg[(size_t)r * 512 + c], aw[512 + c], acc);
    }
    #pragma unroll
    for (int off = 32; off; off >>= 1) acc += __shfl_xor(acc, off, 64);
    if (lane == 0) scores[r] = acc + ab[0];
}

// ---------------- global softmax (unchanged) ----------------
__global__ __launch_bounds__(1024) void softmax_kernel(const float* __restrict__ scores,
                                                       float* __restrict__ wgt) {
    __shared__ float red[1024];
    int t = threadIdx.x;
    float mx = -3.402823466e+38f;
    for (int i = t; i < ROWS; i += 1024) mx = fmaxf(mx, scores[i]);
    red[t] = mx; __syncthreads();
    for (int off = 512; off; off >>= 1) {
        if (t < off) red[t] = fmaxf(red[t], red[t + off]);
        __syncthreads();
    }
    mx = red[0]; __syncthreads();
    float sm = 0.f;
    for (int i = t; i < ROWS; i += 1024) sm += expf(scores[i] - mx);
    red[t] = sm; __syncthreads();
    for (int off = 512; off; off >>= 1) {
        if (t < off) red[t] += red[t + off];
        __syncthreads();
    }
    float denom = red[0];
    for (int i = t; i < ROWS; i += 1024) wgt[i] = expf(scores[i] - mx) / denom;
}

// ---------------- final transpose: UPD[r][c] -> out[b][c][i] ----------------
__global__ __launch_bounds__(256) void transpose_out(const float* __restrict__ UPD,
                                                     float* __restrict__ out) {
    __shared__ float tile[64][65];
    int r0 = blockIdx.x * 64, c0 = blockIdx.y * 64;
    int t = threadIdx.x;
    #pragma unroll
    for (int s = 0; s < 16; ++s) {
        int idx = s * 256 + t;
        int rr = idx >> 6, cc = idx & 63;
        tile[rr][cc] = UPD[(size_t)(r0 + rr) * 512 + c0 + cc];
    }
    __syncthreads();
    #pragma unroll
    for (int s = 0; s < 16; ++s) {
        int idx = s * 256 + t;
        int cc = idx >> 6, rr = idx & 63;
        int r = r0 + rr, c = c0 + cc;
        int b = r / NPT, i = r - b * NPT;
        out[((size_t)b * 512 + c) * NPT + i] = tile[rr][cc];
    }
}

extern "C" void kernel_launch(void* const* d_in, const int* in_sizes, int n_in,
                              void* d_out, int out_size, void* d_ws, size_t ws_size,
                              hipStream_t stream) {
    (void)in_sizes; (void)n_in; (void)out_size; (void)ws_size;
    const float* x       = (const float*)d_in[0];
    const float* fc1_w   = (const float*)d_in[1];
    const float* fc1_b   = (const float*)d_in[2];
    const float* fc2_w   = (const float*)d_in[3];
    const float* fc2_b   = (const float*)d_in[4];
    const float* fce_w   = (const float*)d_in[5];
    const float* fce_b   = (const float*)d_in[6];
    const float* inout_w = (const float*)d_in[7];
    const float* inout_b = (const float*)d_in[8];
    const float* attn_w  = (const float*)d_in[9];
    const float* attn_b  = (const float*)d_in[10];
    const float* upd_w   = (const float*)d_in[11];
    const float* upd_b   = (const float*)d_in[12];
    const float* kp_w    = (const float*)d_in[13];
    const float* kp_b    = (const float*)d_in[14];
    const float* enc_w   = (const float*)d_in[15];
    const float* enc_b   = (const float*)d_in[16];
    const float* mu_w    = (const float*)d_in[17];
    const float* mu_b    = (const float*)d_in[18];
    const float* dec_w   = (const float*)d_in[19];
    const float* dec_b   = (const float*)d_in[20];
    float* out = (float*)d_out;

    char* base = (char*)d_ws;
    size_t o = 0;
    auto alloc = [&](size_t bytes) -> void* {
        void* p = base + o;
        o += (bytes + 255) & ~(size_t)255;
        return p;
    };
    float* qs     = (float*)alloc(ROWS * 4);
    float* degf   = (float*)alloc(ROWS * 4);
    float* scores = (float*)alloc(ROWS * 4);
    float* wgt    = (float*)alloc(ROWS * 4);
    int*   kint   = (int*)  alloc(ROWS * 4);
    size_t regionA = o;  // D + nbr + Z get overlaid by UPD later (all dead by then)
    float* D      = (float*)alloc((size_t)128 * NPT * NPT * 4);   // 19.66 MB
    int*   nbr    = (int*)  alloc((size_t)128 * NPT * KNB * 4);   //  0.80 MB
    __bf16* Z     = (__bf16*)alloc((size_t)ROWS * 512 * 2);       // 12.85 MB
    __bf16* H1    = (__bf16*)alloc((size_t)ROWS * 256 * 2);
    __bf16* H2    = (__bf16*)alloc((size_t)ROWS * 256 * 2);
    __bf16* XB    = (__bf16*)alloc((size_t)ROWS * 256 * 2);
    float* XAGG   = (float*)alloc((size_t)ROWS * 512 * 4);
    float* YAGG   = (float*)alloc((size_t)ROWS * 512 * 4);
    __bf16* XIN   = (__bf16*)alloc((size_t)ROWS * 512 * 2);
    __bf16* FUSED = (__bf16*)alloc((size_t)ROWS * 512 * 2);
    __bf16* fc1t  = (__bf16*)alloc((size_t)512 * 256 * 2);
    __bf16* fc2t  = (__bf16*)alloc((size_t)512 * 256 * 2);
    __bf16* fcet  = (__bf16*)alloc((size_t)256 * 512 * 2);
    __bf16* inoutT= (__bf16*)alloc((size_t)256 * 512 * 2);
    __bf16* updT  = (__bf16*)alloc((size_t)1024 * 512 * 2);
    float* UPD    = (float*)(base + regionA);  // 25.69 MB, aliases D+nbr+Z (33.3 MB)

    const int* nbrx = nbr;
    const int* nbry = nbr + (size_t)64 * NPT * KNB;

    // ---- weight prep (bf16, transposed to [N][K]) + x conversion ----
    transpose_w<<<dim3(8, 4),  256, 0, stream>>>(fc1_w,   fc1t,   512, 256);
    transpose_w<<<dim3(8, 4),  256, 0, stream>>>(fc2_w,   fc2t,   512, 256);
    transpose_w<<<dim3(4, 8),  256, 0, stream>>>(fce_w,   fcet,   256, 512);
    transpose_w<<<dim3(4, 8),  256, 0, stream>>>(inout_w, inoutT, 256, 512);
    transpose_w<<<dim3(16, 8), 256, 0, stream>>>(upd_w,   updT,   1024, 512);
    convert_bf16<<<3136, 256, 0, stream>>>(x, XB);

    // ---- exact f32 pipeline: KNN + k-predictor ----
    qs_kernel<<<64, 256, 0, stream>>>(x, qs);
    gram_kernel<<<dim3(4, 4, 128), 256, 0, stream>>>(x, D);
    topk_kernel<<<(128 * NPT) / 4, 256, 0, stream>>>(D, qs, nbr);
    kint_kernel<<<ROWS / 8, 256, 0, stream>>>(x, kp_w, kp_b, enc_w, enc_b,
                                              mu_w, mu_b, dec_w, dec_b, kint, degf);

    // ---- x branch ----
    gather_kernel<0, 0><<<ROWS / 4, 256, 0, stream>>>(x, nbrx, kint, degf, Z);
    mfma_gemm<7, 0><<<dim3(2, 98), 256, 0, stream>>>(
        Z, nullptr, fc1t, fc1_b, degf, nullptr, H1, 512, 256);
    gather_kernel<0, 1><<<ROWS / 4, 256, 0, stream>>>(H1, nbrx, kint, degf, Z);
    mfma_gemm<6, 0><<<dim3(2, 98), 256, 0, stream>>>(
        Z, nullptr, fc2t, fc2_b, degf, nullptr, H2, 512, 256);
    mfma_gemm<0, 0><<<dim3(4, 98), 256, 0, stream>>>(
        H2, nullptr, fcet, fce_b, nullptr, XAGG, nullptr, 256, 512);

    // ---- y branch ----
    gather_kernel<1, 0><<<ROWS / 4, 256, 0, stream>>>(x, nbry, kint, degf, Z);
    mfma_gemm<7, 0><<<dim3(2, 98), 256, 0, stream>>>(
        Z, nullptr, fc1t, fc1_b, degf, nullptr, H1, 512, 256);
    gather_kernel<0, 1><<<ROWS / 4, 256, 0, stream>>>(H1, nbry, kint, degf, Z);
    mfma_gemm<6, 0><<<dim3(2, 98), 256, 0, stream>>>(
        Z, nullptr, fc2t, fc2_b, degf, nullptr, H2, 512, 256);
    mfma_gemm<0, 0><<<dim3(4, 98), 256, 0, stream>>>(
        H2, nullptr, fcet, fce_b, nullptr, YAGG, nullptr, 256, 512);

    // ---- attention fusion ----
    scores_kernel<<<ROWS / 4, 256, 0, stream>>>(XAGG, YAGG, attn_w, attn_b, scores);
    softmax_kernel<<<1, 1024, 0, stream>>>(scores, wgt);
    fuse_mix<<<6272, 256, 0, stream>>>(XAGG, YAGG, wgt, FUSED);

    // ---- xin + final update GEMM + output transpose ----
    mfma_gemm<4, 0><<<dim3(4, 98), 256, 0, stream>>>(
        XB, nullptr, inoutT, inout_b, nullptr, nullptr, XIN, 256, 512);
    mfma_gemm<1, 1><<<dim3(4, 98), 256, 0, stream>>>(
        XIN, FUSED, updT, upd_b, nullptr, UPD, nullptr, 1024, 512);
    transpose_out<<<dim3(196, 8), 256, 0, stream>>>(UPD, out);
}

// Round 3
// 372.238 us; speedup vs baseline: 2.5282x; 1.1941x over previous
//
#include <hip/hip_runtime.h>
#include <cstddef>
#include <cstdint>

constexpr int BATCH = 64;
constexpr int CH    = 256;
constexpr int NPT   = 196;
constexpr int ROWS  = BATCH * NPT;   // 12544
constexpr int BSTRIDE = CH * NPT;    // 50176
constexpr int KNB   = 8;             // position 8 (9th) is never valid: k_int <= 8

typedef __bf16 bf16x8 __attribute__((ext_vector_type(8)));
typedef __bf16 bf16x4 __attribute__((ext_vector_type(4)));
typedef float  f32x4  __attribute__((ext_vector_type(4)));

__device__ __forceinline__ int src_batch(int b) {
    return (b & ~15) | ((b + 1) & 15);
}

__device__ __forceinline__ void gload_lds16(const void* g, void* l) {
    __builtin_amdgcn_global_load_lds(
        (const __attribute__((address_space(1))) void*)g,
        (__attribute__((address_space(3))) void*)l, 16, 0, 0);
}

// ---------------- qs: per-point squared norm (f32-exact) ----------------
__global__ __launch_bounds__(256) void qs_kernel(const float* __restrict__ x,
                                                 float* __restrict__ qs) {
    int b = blockIdx.x;
    int m = threadIdx.x;
    if (m >= NPT) return;
    const float* xb = x + (size_t)b * BSTRIDE;
    float acc = 0.f;
    for (int c = 0; c < CH; ++c) {
        float v = xb[c * NPT + m];
        acc = fmaf(v, v, acc);
    }
    qs[b * NPT + m] = acc;
}

// ---------------- Gram (f32-exact for KNN determinism) ----------------
__global__ __launch_bounds__(256) void gram_kernel(const float* __restrict__ x,
                                                   float* __restrict__ D) {
    __shared__ float As[16][64];
    __shared__ float Bs[16][64];
    int job = blockIdx.z;
    int qb = (job < 64) ? job : job - 64;
    int kb = (job < 64) ? qb : src_batch(qb);
    int i0 = blockIdx.y * 64, j0 = blockIdx.x * 64;
    int t = threadIdx.x;
    int tx = t & 15, ty = t >> 4;
    const float* Mq = x + (size_t)qb * BSTRIDE;
    const float* Mk = x + (size_t)kb * BSTRIDE;
    float acc[4][4] = {};
    for (int k0 = 0; k0 < CH; k0 += 16) {
        int ii = t & 63, kcb = t >> 6;
        #pragma unroll
        for (int rep = 0; rep < 4; ++rep) {
            int kc = kcb + rep * 4;
            int ci = i0 + ii, cj = j0 + ii;
            As[kc][ii] = (ci < NPT) ? Mq[(size_t)(k0 + kc) * NPT + ci] : 0.f;
            Bs[kc][ii] = (cj < NPT) ? Mk[(size_t)(k0 + kc) * NPT + cj] : 0.f;
        }
        __syncthreads();
        #pragma unroll
        for (int kc = 0; kc < 16; ++kc) {
            float a[4], bv[4];
            #pragma unroll
            for (int s = 0; s < 4; ++s) { a[s] = As[kc][ty*4+s]; bv[s] = Bs[kc][tx*4+s]; }
            #pragma unroll
            for (int i = 0; i < 4; ++i)
                #pragma unroll
                for (int j = 0; j < 4; ++j)
                    acc[i][j] = fmaf(a[i], bv[j], acc[i][j]);
        }
        __syncthreads();
    }
    #pragma unroll
    for (int i = 0; i < 4; ++i) {
        int gi = i0 + ty * 4 + i;
        if (gi >= NPT) continue;
        #pragma unroll
        for (int j = 0; j < 4; ++j) {
            int gj = j0 + tx * 4 + j;
            if (gj < NPT)
                D[(size_t)job * (NPT * NPT) + (size_t)gi * NPT + gj] = acc[i][j];
        }
    }
}

// ---------------- top-8 selection ----------------
__global__ __launch_bounds__(256) void topk_kernel(const float* __restrict__ D,
                                                   const float* __restrict__ qs,
                                                   int* __restrict__ nbr) {
    int wid = threadIdx.x >> 6;
    int lane = threadIdx.x & 63;
    int rowid = blockIdx.x * 4 + wid;
    int job = rowid / NPT;
    int i = rowid - job * NPT;
    int qb = (job < 64) ? job : job - 64;
    int kb = (job < 64) ? qb : src_batch(qb);
    const float* drow = D + (size_t)job * (NPT * NPT) + (size_t)i * NPT;
    float qsi = qs[qb * NPT + i];
    const float* ksr = qs + kb * NPT;
    float dist[4];
    #pragma unroll
    for (int s = 0; s < 4; ++s) {
        int m = lane + 64 * s;
        dist[s] = (m < NPT) ? (qsi - 2.f * drow[m] + ksr[m])
                            : __uint_as_float(0x7f800000u);
    }
    for (int it = 0; it < KNB; ++it) {
        unsigned long long best = ~0ull;
        #pragma unroll
        for (int s = 0; s < 4; ++s) {
            unsigned u = __float_as_uint(dist[s]);
            u = (u & 0x80000000u) ? ~u : (u | 0x80000000u);
            unsigned long long key = ((unsigned long long)u << 32) |
                                     (unsigned)(lane + 64 * s);
            if (key < best) best = key;
        }
        #pragma unroll
        for (int off = 32; off; off >>= 1) {
            unsigned long long o = __shfl_xor(best, off, 64);
            if (o < best) best = o;
        }
        int widx = (int)(best & 0xffffffffu);
        if (lane == (widx & 63)) dist[widx >> 6] = __uint_as_float(0x7f800000u);
        if (lane == 0) nbr[(size_t)rowid * KNB + it] = widx;
    }
}

// ---------------- compose W1 = kp_w @ enc_w (f64 accum), b1 = kp_b @ enc_w + enc_b ----------------
__global__ __launch_bounds__(256) void compose_w1(const float* __restrict__ kp_w,
        const float* __restrict__ kp_b, const float* __restrict__ enc_w,
        const float* __restrict__ enc_b, float* __restrict__ W1,
        float* __restrict__ b1) {
    int b = blockIdx.x;
    if (b < 64) {
        int i = b * 4 + (threadIdx.x >> 6);
        int j = threadIdx.x & 63;
        double acc = 0.0;
        for (int k = 0; k < 500; ++k)
            acc += (double)kp_w[(size_t)i * 500 + k] * (double)enc_w[(size_t)k * 64 + j];
        W1[i * 64 + j] = (float)acc;
    } else {
        int j = threadIdx.x;
        if (j < 64) {
            double acc = (double)enc_b[j];
            for (int k = 0; k < 500; ++k)
                acc += (double)kp_b[k] * (double)enc_w[(size_t)k * 64 + j];
            b1[j] = (float)acc;
        }
    }
}

// ---------------- compose W2 = mu_w @ dec_w (f64 accum), b2 = mu_b @ dec_w + dec_b ----------------
__global__ __launch_bounds__(256) void compose_w2(const float* __restrict__ mu_w,
        const float* __restrict__ mu_b, const float* __restrict__ dec_w,
        const float* __restrict__ dec_b, float* __restrict__ W2,
        float* __restrict__ b2) {
    int t = blockIdx.x * 256 + threadIdx.x;
    if (t < 576) {
        int i = t / 9, j = t - (t / 9) * 9;
        double acc = 0.0;
        for (int k = 0; k < 32; ++k)
            acc += (double)mu_w[(size_t)i * 32 + k] * (double)dec_w[(size_t)k * 9 + j];
        W2[t] = (float)acc;
    } else if (t < 585) {
        int j = t - 576;
        double acc = (double)dec_b[j];
        for (int k = 0; k < 32; ++k)
            acc += (double)mu_b[k] * (double)dec_w[(size_t)k * 9 + j];
        b2[j] = (float)acc;
    }
}

// ---------------- collapsed k-predictor: e=relu(x@W1+b1); logits=e@W2+b2; argmax ----------------
__global__ __launch_bounds__(256) void kint2_kernel(const float* __restrict__ x,
    const float* __restrict__ W1, const float* __restrict__ b1,
    const float* __restrict__ W2, const float* __restrict__ b2,
    int* __restrict__ kint, float* __restrict__ degf) {
    __shared__ __attribute__((aligned(16))) float xr[16][256];
    __shared__ float ebuf[16][64];
    __shared__ float lg[16][9];
    int t = threadIdx.x;
    int r0 = blockIdx.x * 16;
    const float4* xg = (const float4*)(x + (size_t)r0 * 256);
    float4* xs = (float4*)&xr[0][0];
    #pragma unroll
    for (int s = 0; s < 4; ++s) xs[s * 256 + t] = xg[s * 256 + t];
    __syncthreads();
    int w = t >> 6, l = t & 63;
    {
        float bb = b1[l];
        float a0 = bb, a1 = bb, a2 = bb, a3 = bb;
        const float* x0 = xr[w * 4 + 0];
        const float* x1 = xr[w * 4 + 1];
        const float* x2 = xr[w * 4 + 2];
        const float* x3 = xr[w * 4 + 3];
        for (int c = 0; c < 256; ++c) {
            float wv = W1[c * 64 + l];
            a0 = fmaf(x0[c], wv, a0);
            a1 = fmaf(x1[c], wv, a1);
            a2 = fmaf(x2[c], wv, a2);
            a3 = fmaf(x3[c], wv, a3);
        }
        ebuf[w * 4 + 0][l] = fmaxf(a0, 0.f);
        ebuf[w * 4 + 1][l] = fmaxf(a1, 0.f);
        ebuf[w * 4 + 2][l] = fmaxf(a2, 0.f);
        ebuf[w * 4 + 3][l] = fmaxf(a3, 0.f);
    }
    __syncthreads();
    int rr = t >> 4, cc = t & 15;
    if (cc < 9) {
        float acc = b2[cc];
        for (int j = 0; j < 64; ++j)
            acc = fmaf(ebuf[rr][j], W2[j * 9 + cc], acc);
        lg[rr][cc] = acc;
    }
    __syncthreads();
    if (cc == 0) {
        float best = lg[rr][0];
        int bi = 0;
        #pragma unroll
        for (int j = 1; j < 9; ++j)
            if (lg[rr][j] > best) { best = lg[rr][j]; bi = j; }
        kint[r0 + rr] = bi;
        degf[r0 + rr] = (float)bi;
    }
}

// ---------------- gather: Z(bf16) = [deg*feat | nbr_sum - deg*feat] ----------------
template<int REMAP, int BF16IN>
__global__ __launch_bounds__(256) void gather_kernel(const void* __restrict__ featv,
        const int* __restrict__ nbr, const int* __restrict__ kint_,
        const float* __restrict__ degf, __bf16* __restrict__ Z) {
    int g = threadIdx.x >> 6, lane = threadIdx.x & 63;
    int r = blockIdx.x * 4 + g;
    int b = r / NPT, i = r - b * NPT;
    int fb = REMAP ? src_batch(b) : b;
    float sv[4];
    if constexpr (BF16IN) {
        const __bf16* feat = (const __bf16*)featv;
        bf16x4 v = *(const bf16x4*)(feat + ((size_t)fb * NPT + i) * CH + lane * 4);
        #pragma unroll
        for (int j = 0; j < 4; ++j) sv[j] = (float)v[j];
    } else {
        const float* feat = (const float*)featv;
        float4 v = *(const float4*)(feat + ((size_t)fb * NPT + i) * CH + lane * 4);
        sv[0] = v.x; sv[1] = v.y; sv[2] = v.z; sv[3] = v.w;
    }
    float s[4] = {0.f, 0.f, 0.f, 0.f};
    int kk = kint_[r];
    const int* nb = nbr + (size_t)r * KNB;
    for (int tt = 0; tt < kk; ++tt) {
        int m = nb[tt];
        if constexpr (BF16IN) {
            const __bf16* feat = (const __bf16*)featv;
            bf16x4 v = *(const bf16x4*)(feat + ((size_t)fb * NPT + m) * CH + lane * 4);
            #pragma unroll
            for (int j = 0; j < 4; ++j) s[j] += (float)v[j];
        } else {
            const float* feat = (const float*)featv;
            float4 v = *(const float4*)(feat + ((size_t)fb * NPT + m) * CH + lane * 4);
            s[0] += v.x; s[1] += v.y; s[2] += v.z; s[3] += v.w;
        }
    }
    float dg = degf[r];
    bf16x4 av, dv;
    #pragma unroll
    for (int j = 0; j < 4; ++j) {
        float a = dg * sv[j];
        av[j] = (__bf16)a;
        dv[j] = (__bf16)(s[j] - a);
    }
    *(bf16x4*)(Z + (size_t)r * 512 + lane * 4) = av;
    *(bf16x4*)(Z + (size_t)r * 512 + 256 + lane * 4) = dv;
}

// ---------------- bf16 MFMA GEMM: C = op(A @ W + [deg*]bias) ----------------
// FLAGS: 1=RELU, 2=DEG-scaled bias, 4=bf16 output (else f32).
template<int FLAGS, int CONCAT>
__global__ __launch_bounds__(256) void mfma_gemm(
    const __bf16* __restrict__ A0, const __bf16* __restrict__ A1,
    const __bf16* __restrict__ WT, const float* __restrict__ bias,
    const float* __restrict__ degf, float* __restrict__ Cf,
    __bf16* __restrict__ Cb, int K, int N) {
    __shared__ __attribute__((aligned(16))) __bf16 As[128 * 64];
    __shared__ __attribute__((aligned(16))) __bf16 Bs[128 * 64];
    int t = threadIdx.x, w = t >> 6, l = t & 63;
    int r0 = blockIdx.y * 128, c0 = blockIdx.x * 128;
    int lr = l & 15, lg = l >> 4;
    int wr = (w >> 1) * 64, wc = (w & 1) * 64;
    f32x4 acc[4][4] = {};
    for (int k0 = 0; k0 < K; k0 += 64) {
        const __bf16* Ab = A0;
        int kk = k0;
        size_t KA = CONCAT ? 512 : (size_t)K;
        if (CONCAT && k0 >= 512) { Ab = A1; kk = k0 - 512; }
        #pragma unroll
        for (int i = 0; i < 4; ++i) {
            int row = (w * 4 + i) * 8 + (l >> 3);
            int c8 = l & 7;
            gload_lds16(Ab + (size_t)(r0 + row) * KA + kk + c8 * 8,
                        As + (w * 4 + i) * 512);
            gload_lds16(WT + (size_t)(c0 + row) * K + k0 + c8 * 8,
                        Bs + (w * 4 + i) * 512);
        }
        asm volatile("s_waitcnt vmcnt(0)" ::: "memory");
        __syncthreads();
        #pragma unroll
        for (int ks = 0; ks < 2; ++ks) {
            bf16x8 af[4], bfr[4];
            #pragma unroll
            for (int mi = 0; mi < 4; ++mi)
                af[mi] = *(const bf16x8*)(As + (wr + mi * 16 + lr) * 64 + ks * 32 + lg * 8);
            #pragma unroll
            for (int ni = 0; ni < 4; ++ni)
                bfr[ni] = *(const bf16x8*)(Bs + (wc + ni * 16 + lr) * 64 + ks * 32 + lg * 8);
            #pragma unroll
            for (int mi = 0; mi < 4; ++mi)
                #pragma unroll
                for (int ni = 0; ni < 4; ++ni)
                    acc[mi][ni] = __builtin_amdgcn_mfma_f32_16x16x32_bf16(
                        af[mi], bfr[ni], acc[mi][ni], 0, 0, 0);
        }
        __syncthreads();
    }
    #pragma unroll
    for (int mi = 0; mi < 4; ++mi) {
        #pragma unroll
        for (int r = 0; r < 4; ++r) {
            int row = r0 + wr + mi * 16 + lg * 4 + r;
            float dsc = 1.f;
            if constexpr ((FLAGS & 2) != 0) dsc = degf[row];
            #pragma unroll
            for (int ni = 0; ni < 4; ++ni) {
                int col = c0 + wc + ni * 16 + lr;
                float v = acc[mi][ni][r] + dsc * bias[col];
                if constexpr ((FLAGS & 1) != 0) v = fmaxf(v, 0.f);
                if constexpr ((FLAGS & 4) != 0)
                    Cb[(size_t)row * N + col] = (__bf16)v;
                else
                    Cf[(size_t)row * N + col] = v;
            }
        }
    }
}

// ---------------- weight transpose + f32->bf16: WT[n][k] = W[k][n] ----------------
__global__ __launch_bounds__(256) void transpose_w(const float* __restrict__ W,
        __bf16* __restrict__ WT, int K, int N) {
    __shared__ float tile[64][65];
    int k0 = blockIdx.x * 64, n0 = blockIdx.y * 64;
    int t = threadIdx.x;
    #pragma unroll
    for (int s = 0; s < 16; ++s) {
        int idx = s * 256 + t;
        int kk = idx >> 6, nn = idx & 63;
        tile[kk][nn] = W[(size_t)(k0 + kk) * N + n0 + nn];
    }
    __syncthreads();
    #pragma unroll
    for (int s = 0; s < 16; ++s) {
        int idx = s * 256 + t;
        int nn = idx >> 6, kk = idx & 63;
        WT[(size_t)(n0 + nn) * K + k0 + kk] = (__bf16)tile[kk][nn];
    }
}

// ---------------- flat f32 -> bf16 ----------------
__global__ __launch_bounds__(256) void convert_bf16(const float* __restrict__ src,
                                                    __bf16* __restrict__ dst) {
    int idx = blockIdx.x * 256 + threadIdx.x;
    float4 v = *(const float4*)(src + (size_t)idx * 4);
    bf16x4 o;
    o[0] = (__bf16)v.x; o[1] = (__bf16)v.y; o[2] = (__bf16)v.z; o[3] = (__bf16)v.w;
    *(bf16x4*)(dst + (size_t)idx * 4) = o;
}

// ---------------- fused mix: FUSED(bf16) = wgt*XAGG + (1-wgt)*YAGG ----------------
__global__ __launch_bounds__(256) void fuse_mix(const float* __restrict__ XA,
        const float* __restrict__ YA, const float* __restrict__ wgt,
        __bf16* __restrict__ F) {
    int idx = blockIdx.x * 256 + threadIdx.x;
    size_t e0 = (size_t)idx * 4;
    int r = (int)(e0 >> 9);
    float wv = wgt[r];
    float4 xv = *(const float4*)(XA + e0);
    float4 yv = *(const float4*)(YA + e0);
    bf16x4 o;
    o[0] = (__bf16)(wv * xv.x + (1.f - wv) * yv.x);
    o[1] = (__bf16)(wv * xv.y + (1.f - wv) * yv.y);
    o[2] = (__bf16)(wv * xv.z + (1.f - wv) * yv.z);
    o[3] = (__bf16)(wv * xv.w + (1.f - wv) * yv.w);
    *(bf16x4*)(F + e0) = o;
}

// ---------------- attention scores (f32) ----------------
__global__ __launch_bounds__(256) void scores_kernel(const float* __restrict__ xagg,
        const float* __restrict__ yagg, const float* __restrict__ aw,
        const float* __restrict__ ab, float* __restrict__ scores) {
    int g = threadIdx.x >> 6, lane = threadIdx.x & 63;
    int r = blockIdx.x * 4 + g;
    float acc = 0.f;
    #pragma unroll
    for (int s = 0; s < 8; ++s) {
        int c = lane + 64 * s;
        acc = fmaf(xagg[(size_t)r * 512 + c], aw[c], acc);
        acc = fmaf(yagg[(size_t)r * 512 + c], aw[512 + c], acc);
    }
    #pragma unroll
    for (int off = 32; off; off >>= 1) acc += __shfl_xor(acc, off, 64);
    if (lane == 0) scores[r] = acc + ab[0];
}

// ---------------- global softmax ----------------
__global__ __launch_bounds__(1024) void softmax_kernel(const float* __restrict__ scores,
                                                       float* __restrict__ wgt) {
    __shared__ float red[1024];
    int t = threadIdx.x;
    float mx = -3.402823466e+38f;
    for (int i = t; i < ROWS; i += 1024) mx = fmaxf(mx, scores[i]);
    red[t] = mx; __syncthreads();
    for (int off = 512; off; off >>= 1) {
        if (t < off) red[t] = fmaxf(red[t], red[t + off]);
        __syncthreads();
    }
    mx = red[0]; __syncthreads();
    float sm = 0.f;
    for (int i = t; i < ROWS; i += 1024) sm += expf(scores[i] - mx);
    red[t] = sm; __syncthreads();
    for (int off = 512; off; off >>= 1) {
        if (t < off) red[t] += red[t + off];
        __syncthreads();
    }
    float denom = red[0];
    for (int i = t; i < ROWS; i += 1024) wgt[i] = expf(scores[i] - mx) / denom;
}

// ---------------- final transpose: UPD[r][c] -> out[b][c][i] ----------------
__global__ __launch_bounds__(256) void transpose_out(const float* __restrict__ UPD,
                                                     float* __restrict__ out) {
    __shared__ float tile[64][65];
    int r0 = blockIdx.x * 64, c0 = blockIdx.y * 64;
    int t = threadIdx.x;
    #pragma unroll
    for (int s = 0; s < 16; ++s) {
        int idx = s * 256 + t;
        int rr = idx >> 6, cc = idx & 63;
        tile[rr][cc] = UPD[(size_t)(r0 + rr) * 512 + c0 + cc];
    }
    __syncthreads();
    #pragma unroll
    for (int s = 0; s < 16; ++s) {
        int idx = s * 256 + t;
        int cc = idx >> 6, rr = idx & 63;
        int r = r0 + rr, c = c0 + cc;
        int b = r / NPT, i = r - b * NPT;
        out[((size_t)b * 512 + c) * NPT + i] = tile[rr][cc];
    }
}

extern "C" void kernel_launch(void* const* d_in, const int* in_sizes, int n_in,
                              void* d_out, int out_size, void* d_ws, size_t ws_size,
                              hipStream_t stream) {
    (void)in_sizes; (void)n_in; (void)out_size; (void)ws_size;
    const float* x       = (const float*)d_in[0];
    const float* fc1_w   = (const float*)d_in[1];
    const float* fc1_b   = (const float*)d_in[2];
    const float* fc2_w   = (const float*)d_in[3];
    const float* fc2_b   = (const float*)d_in[4];
    const float* fce_w   = (const float*)d_in[5];
    const float* fce_b   = (const float*)d_in[6];
    const float* inout_w = (const float*)d_in[7];
    const float* inout_b = (const float*)d_in[8];
    const float* attn_w  = (const float*)d_in[9];
    const float* attn_b  = (const float*)d_in[10];
    const float* upd_w   = (const float*)d_in[11];
    const float* upd_b   = (const float*)d_in[12];
    const float* kp_w    = (const float*)d_in[13];
    const float* kp_b    = (const float*)d_in[14];
    const float* enc_w   = (const float*)d_in[15];
    const float* enc_b   = (const float*)d_in[16];
    const float* mu_w    = (const float*)d_in[17];
    const float* mu_b    = (const float*)d_in[18];
    const float* dec_w   = (const float*)d_in[19];
    const float* dec_b   = (const float*)d_in[20];
    float* out = (float*)d_out;

    char* base = (char*)d_ws;
    size_t o = 0;
    auto alloc = [&](size_t bytes) -> void* {
        void* p = base + o;
        o += (bytes + 255) & ~(size_t)255;
        return p;
    };
    float* qs     = (float*)alloc(ROWS * 4);
    float* degf   = (float*)alloc(ROWS * 4);
    float* scores = (float*)alloc(ROWS * 4);
    float* wgt    = (float*)alloc(ROWS * 4);
    int*   kint   = (int*)  alloc(ROWS * 4);
    float* W1     = (float*)alloc(256 * 64 * 4);
    float* b1     = (float*)alloc(64 * 4);
    float* W2     = (float*)alloc(64 * 9 * 4);
    float* b2     = (float*)alloc(9 * 4);
    size_t regionA = o;  // D + nbr + Z get overlaid by UPD later (all dead by then)
    float* D      = (float*)alloc((size_t)128 * NPT * NPT * 4);   // 19.66 MB
    int*   nbr    = (int*)  alloc((size_t)128 * NPT * KNB * 4);   //  0.80 MB
    __bf16* Z     = (__bf16*)alloc((size_t)ROWS * 512 * 2);       // 12.85 MB
    __bf16* H1    = (__bf16*)alloc((size_t)ROWS * 256 * 2);
    __bf16* H2    = (__bf16*)alloc((size_t)ROWS * 256 * 2);
    __bf16* XB    = (__bf16*)alloc((size_t)ROWS * 256 * 2);
    float* XAGG   = (float*)alloc((size_t)ROWS * 512 * 4);
    float* YAGG   = (float*)alloc((size_t)ROWS * 512 * 4);
    __bf16* XIN   = (__bf16*)alloc((size_t)ROWS * 512 * 2);
    __bf16* FUSED = (__bf16*)alloc((size_t)ROWS * 512 * 2);
    __bf16* fc1t  = (__bf16*)alloc((size_t)512 * 256 * 2);
    __bf16* fc2t  = (__bf16*)alloc((size_t)512 * 256 * 2);
    __bf16* fcet  = (__bf16*)alloc((size_t)256 * 512 * 2);
    __bf16* inoutT= (__bf16*)alloc((size_t)256 * 512 * 2);
    __bf16* updT  = (__bf16*)alloc((size_t)1024 * 512 * 2);
    float* UPD    = (float*)(base + regionA);  // 25.69 MB, aliases D+nbr+Z (33.3 MB)

    const int* nbrx = nbr;
    const int* nbry = nbr + (size_t)64 * NPT * KNB;

    // ---- weight prep: transposes, bf16 conversion, composed k-predictor ----
    transpose_w<<<dim3(8, 4),  256, 0, stream>>>(fc1_w,   fc1t,   512, 256);
    transpose_w<<<dim3(8, 4),  256, 0, stream>>>(fc2_w,   fc2t,   512, 256);
    transpose_w<<<dim3(4, 8),  256, 0, stream>>>(fce_w,   fcet,   256, 512);
    transpose_w<<<dim3(4, 8),  256, 0, stream>>>(inout_w, inoutT, 256, 512);
    transpose_w<<<dim3(16, 8), 256, 0, stream>>>(upd_w,   updT,   1024, 512);
    convert_bf16<<<3136, 256, 0, stream>>>(x, XB);
    compose_w1<<<65, 256, 0, stream>>>(kp_w, kp_b, enc_w, enc_b, W1, b1);
    compose_w2<<<3, 256, 0, stream>>>(mu_w, mu_b, dec_w, dec_b, W2, b2);

    // ---- exact f32 pipeline: KNN + collapsed k-predictor ----
    qs_kernel<<<64, 256, 0, stream>>>(x, qs);
    gram_kernel<<<dim3(4, 4, 128), 256, 0, stream>>>(x, D);
    topk_kernel<<<(128 * NPT) / 4, 256, 0, stream>>>(D, qs, nbr);
    kint2_kernel<<<ROWS / 16, 256, 0, stream>>>(x, W1, b1, W2, b2, kint, degf);

    // ---- x branch ----
    gather_kernel<0, 0><<<ROWS / 4, 256, 0, stream>>>(x, nbrx, kint, degf, Z);
    mfma_gemm<7, 0><<<dim3(2, 98), 256, 0, stream>>>(
        Z, nullptr, fc1t, fc1_b, degf, nullptr, H1, 512, 256);
    gather_kernel<0, 1><<<ROWS / 4, 256, 0, stream>>>(H1, nbrx, kint, degf, Z);
    mfma_gemm<6, 0><<<dim3(2, 98), 256, 0, stream>>>(
        Z, nullptr, fc2t, fc2_b, degf, nullptr, H2, 512, 256);
    mfma_gemm<0, 0><<<dim3(4, 98), 256, 0, stream>>>(
        H2, nullptr, fcet, fce_b, nullptr, XAGG, nullptr, 256, 512);

    // ---- y branch ----
    gather_kernel<1, 0><<<ROWS / 4, 256, 0, stream>>>(x, nbry, kint, degf, Z);
    mfma_gemm<7, 0><<<dim3(2, 98), 256, 0, stream>>>(
        Z, nullptr, fc1t, fc1_b, degf, nullptr, H1, 512, 256);
    gather_kernel<0, 1><<<ROWS / 4, 256, 0, stream>>>(H1, nbry, kint, degf, Z);
    mfma_gemm<6, 0><<<dim3(2, 98), 256, 0, stream>>>(
        Z, nullptr, fc2t, fc2_b, degf, nullptr, H2, 512, 256);
    mfma_gemm<0, 0><<<dim3(4, 98), 256, 0, stream>>>(
        H2, nullptr, fcet, fce_b, nullptr, YAGG, nullptr, 256, 512);

    // ---- attention fusion ----
    scores_kernel<<<ROWS / 4, 256, 0, stream>>>(XAGG, YAGG, attn_w, attn_b, scores);
    softmax_kernel<<<1, 1024, 0, stream>>>(scores, wgt);
    fuse_mix<<<6272, 256, 0, stream>>>(XAGG, YAGG, wgt, FUSED);

    // ---- xin + final update GEMM + output transpose ----
    mfma_gemm<4, 0><<<dim3(4, 98), 256, 0, stream>>>(
        XB, nullptr, inoutT, inout_b, nullptr, nullptr, XIN, 256, 512);
    mfma_gemm<1, 1><<<dim3(4, 98), 256, 0, stream>>>(
        XIN, FUSED, updT, upd_b, nullptr, UPD, nullptr, 1024, 512);
    transpose_out<<<dim3(196, 8), 256, 0, stream>>>(UPD, out);
}

// Round 4
// 335.011 us; speedup vs baseline: 2.8091x; 1.1111x over previous
//
#include <hip/hip_runtime.h>
#include <cstddef>
#include <cstdint>

constexpr int BATCH = 64;
constexpr int CH    = 256;
constexpr int NPT   = 196;
constexpr int ROWS  = BATCH * NPT;   // 12544
constexpr int BSTRIDE = CH * NPT;    // 50176
constexpr int KNB   = 8;             // position 8 (9th) is never valid: k_int <= 8

typedef __bf16 bf16x8 __attribute__((ext_vector_type(8)));
typedef __bf16 bf16x4 __attribute__((ext_vector_type(4)));
typedef _Float16 f16x8 __attribute__((ext_vector_type(8)));
typedef float  f32x4  __attribute__((ext_vector_type(4)));

__device__ __forceinline__ int src_batch(int b) {
    return (b & ~15) | ((b + 1) & 15);
}

__device__ __forceinline__ void gload_lds16(const void* g, void* l) {
    __builtin_amdgcn_global_load_lds(
        (const __attribute__((address_space(1))) void*)g,
        (__attribute__((address_space(3))) void*)l, 16, 0, 0);
}

// ---------------- qs: per-point squared norm (f32-exact) ----------------
__global__ __launch_bounds__(256) void qs_kernel(const float* __restrict__ x,
                                                 float* __restrict__ qs) {
    int b = blockIdx.x;
    int m = threadIdx.x;
    if (m >= NPT) return;
    const float* xb = x + (size_t)b * BSTRIDE;
    float acc = 0.f;
    for (int c = 0; c < CH; ++c) {
        float v = xb[c * NPT + m];
        acc = fmaf(v, v, acc);
    }
    qs[b * NPT + m] = acc;
}

// ---------------- transpose + f16 hi/lo split: x[b][c][m] -> XH/XL[b][m][c], m padded to 256 ----------------
__global__ __launch_bounds__(256) void trans_split(const float* __restrict__ x,
        _Float16* __restrict__ XH, _Float16* __restrict__ XL) {
    __shared__ float tile[64][65];
    int b = blockIdx.z;
    int m0 = blockIdx.x * 64, c0 = blockIdx.y * 64;
    int t = threadIdx.x;
    const float* xb = x + (size_t)b * BSTRIDE;
    #pragma unroll
    for (int s = 0; s < 16; ++s) {
        int idx = s * 256 + t;
        int cc = idx >> 6, mm = idx & 63;
        int m = m0 + mm;
        tile[cc][mm] = (m < NPT) ? xb[(size_t)(c0 + cc) * NPT + m] : 0.f;
    }
    __syncthreads();
    #pragma unroll
    for (int s = 0; s < 16; ++s) {
        int idx = s * 256 + t;
        int mm = idx >> 6, cc = idx & 63;
        float v = tile[cc][mm];
        _Float16 h = (_Float16)v;
        size_t off = ((size_t)b * 256 + (m0 + mm)) * 256 + c0 + cc;
        XH[off] = h;
        XL[off] = (_Float16)(v - (float)h);
    }
}

// ---------------- Gram via f16-split MFMA: D = Ah*Bh + Ah*Bl + Al*Bh (f32-quality) ----------------
__global__ __launch_bounds__(256) void gram_mfma(const _Float16* __restrict__ XH,
        const _Float16* __restrict__ XL, float* __restrict__ D) {
    __shared__ __attribute__((aligned(16))) _Float16 Ah[128 * 64];
    __shared__ __attribute__((aligned(16))) _Float16 Al[128 * 64];
    __shared__ __attribute__((aligned(16))) _Float16 Bh[128 * 64];
    __shared__ __attribute__((aligned(16))) _Float16 Bl[128 * 64];
    int job = blockIdx.z;
    int qb = (job < 64) ? job : job - 64;
    int kb = (job < 64) ? qb : src_batch(qb);
    int t = threadIdx.x, w = t >> 6, l = t & 63;
    int r0 = blockIdx.y * 128, c0 = blockIdx.x * 128;
    int lr = l & 15, lg = l >> 4;
    int wr = (w >> 1) * 64, wc = (w & 1) * 64;
    const _Float16* qh = XH + (size_t)qb * 65536;
    const _Float16* ql = XL + (size_t)qb * 65536;
    const _Float16* kh = XH + (size_t)kb * 65536;
    const _Float16* kl = XL + (size_t)kb * 65536;
    f32x4 acc[4][4] = {};
    for (int k0 = 0; k0 < 256; k0 += 64) {
        #pragma unroll
        for (int i = 0; i < 4; ++i) {
            int row = (w * 4 + i) * 8 + (l >> 3);
            int c8 = l & 7;
            size_t goA = (size_t)(r0 + row) * 256 + k0 + c8 * 8;
            size_t goB = (size_t)(c0 + row) * 256 + k0 + c8 * 8;
            gload_lds16(qh + goA, Ah + (w * 4 + i) * 512);
            gload_lds16(ql + goA, Al + (w * 4 + i) * 512);
            gload_lds16(kh + goB, Bh + (w * 4 + i) * 512);
            gload_lds16(kl + goB, Bl + (w * 4 + i) * 512);
        }
        asm volatile("s_waitcnt vmcnt(0)" ::: "memory");
        __syncthreads();
        #pragma unroll
        for (int ks = 0; ks < 2; ++ks) {
            f16x8 ah[4], al[4], bh[4], bl[4];
            #pragma unroll
            for (int mi = 0; mi < 4; ++mi) {
                ah[mi] = *(const f16x8*)(Ah + (wr + mi * 16 + lr) * 64 + ks * 32 + lg * 8);
                al[mi] = *(const f16x8*)(Al + (wr + mi * 16 + lr) * 64 + ks * 32 + lg * 8);
            }
            #pragma unroll
            for (int ni = 0; ni < 4; ++ni) {
                bh[ni] = *(const f16x8*)(Bh + (wc + ni * 16 + lr) * 64 + ks * 32 + lg * 8);
                bl[ni] = *(const f16x8*)(Bl + (wc + ni * 16 + lr) * 64 + ks * 32 + lg * 8);
            }
            #pragma unroll
            for (int mi = 0; mi < 4; ++mi)
                #pragma unroll
                for (int ni = 0; ni < 4; ++ni) {
                    acc[mi][ni] = __builtin_amdgcn_mfma_f32_16x16x32_f16(
                        ah[mi], bh[ni], acc[mi][ni], 0, 0, 0);
                    acc[mi][ni] = __builtin_amdgcn_mfma_f32_16x16x32_f16(
                        ah[mi], bl[ni], acc[mi][ni], 0, 0, 0);
                    acc[mi][ni] = __builtin_amdgcn_mfma_f32_16x16x32_f16(
                        al[mi], bh[ni], acc[mi][ni], 0, 0, 0);
                }
        }
        __syncthreads();
    }
    #pragma unroll
    for (int mi = 0; mi < 4; ++mi) {
        #pragma unroll
        for (int r = 0; r < 4; ++r) {
            int gi = r0 + wr + mi * 16 + lg * 4 + r;
            if (gi >= NPT) continue;
            #pragma unroll
            for (int ni = 0; ni < 4; ++ni) {
                int gj = c0 + wc + ni * 16 + lr;
                if (gj < NPT)
                    D[(size_t)job * (NPT * NPT) + (size_t)gi * NPT + gj] =
                        acc[mi][ni][r];
            }
        }
    }
}

// ---------------- top-8 selection ----------------
__global__ __launch_bounds__(256) void topk_kernel(const float* __restrict__ D,
                                                   const float* __restrict__ qs,
                                                   int* __restrict__ nbr) {
    int wid = threadIdx.x >> 6;
    int lane = threadIdx.x & 63;
    int rowid = blockIdx.x * 4 + wid;
    int job = rowid / NPT;
    int i = rowid - job * NPT;
    int qb = (job < 64) ? job : job - 64;
    int kb = (job < 64) ? qb : src_batch(qb);
    const float* drow = D + (size_t)job * (NPT * NPT) + (size_t)i * NPT;
    float qsi = qs[qb * NPT + i];
    const float* ksr = qs + kb * NPT;
    float dist[4];
    #pragma unroll
    for (int s = 0; s < 4; ++s) {
        int m = lane + 64 * s;
        dist[s] = (m < NPT) ? (qsi - 2.f * drow[m] + ksr[m])
                            : __uint_as_float(0x7f800000u);
    }
    for (int it = 0; it < KNB; ++it) {
        unsigned long long best = ~0ull;
        #pragma unroll
        for (int s = 0; s < 4; ++s) {
            unsigned u = __float_as_uint(dist[s]);
            u = (u & 0x80000000u) ? ~u : (u | 0x80000000u);
            unsigned long long key = ((unsigned long long)u << 32) |
                                     (unsigned)(lane + 64 * s);
            if (key < best) best = key;
        }
        #pragma unroll
        for (int off = 32; off; off >>= 1) {
            unsigned long long o = __shfl_xor(best, off, 64);
            if (o < best) best = o;
        }
        int widx = (int)(best & 0xffffffffu);
        if (lane == (widx & 63)) dist[widx >> 6] = __uint_as_float(0x7f800000u);
        if (lane == 0) nbr[(size_t)rowid * KNB + it] = widx;
    }
}

// ---------------- compose W1 = kp_w @ enc_w (f64 accum), b1 = kp_b @ enc_w + enc_b ----------------
__global__ __launch_bounds__(256) void compose_w1(const float* __restrict__ kp_w,
        const float* __restrict__ kp_b, const float* __restrict__ enc_w,
        const float* __restrict__ enc_b, float* __restrict__ W1,
        float* __restrict__ b1) {
    int b = blockIdx.x;
    if (b < 64) {
        int i = b * 4 + (threadIdx.x >> 6);
        int j = threadIdx.x & 63;
        double acc = 0.0;
        for (int k = 0; k < 500; ++k)
            acc += (double)kp_w[(size_t)i * 500 + k] * (double)enc_w[(size_t)k * 64 + j];
        W1[i * 64 + j] = (float)acc;
    } else {
        int j = threadIdx.x;
        if (j < 64) {
            double acc = (double)enc_b[j];
            for (int k = 0; k < 500; ++k)
                acc += (double)kp_b[k] * (double)enc_w[(size_t)k * 64 + j];
            b1[j] = (float)acc;
        }
    }
}

// ---------------- compose W2 = mu_w @ dec_w (f64 accum), b2 = mu_b @ dec_w + dec_b ----------------
__global__ __launch_bounds__(256) void compose_w2(const float* __restrict__ mu_w,
        const float* __restrict__ mu_b, const float* __restrict__ dec_w,
        const float* __restrict__ dec_b, float* __restrict__ W2,
        float* __restrict__ b2) {
    int t = blockIdx.x * 256 + threadIdx.x;
    if (t < 576) {
        int i = t / 9, j = t - (t / 9) * 9;
        double acc = 0.0;
        for (int k = 0; k < 32; ++k)
            acc += (double)mu_w[(size_t)i * 32 + k] * (double)dec_w[(size_t)k * 9 + j];
        W2[t] = (float)acc;
    } else if (t < 585) {
        int j = t - 576;
        double acc = (double)dec_b[j];
        for (int k = 0; k < 32; ++k)
            acc += (double)mu_b[k] * (double)dec_w[(size_t)k * 9 + j];
        b2[j] = (float)acc;
    }
}

// ---------------- collapsed k-predictor: e=relu(x@W1+b1); logits=e@W2+b2; argmax ----------------
__global__ __launch_bounds__(256) void kint2_kernel(const float* __restrict__ x,
    const float* __restrict__ W1, const float* __restrict__ b1,
    const float* __restrict__ W2, const float* __restrict__ b2,
    int* __restrict__ kint, float* __restrict__ degf) {
    __shared__ __attribute__((aligned(16))) float xr[16][256];
    __shared__ float ebuf[16][64];
    __shared__ float lg[16][9];
    int t = threadIdx.x;
    int r0 = blockIdx.x * 16;
    const float4* xg = (const float4*)(x + (size_t)r0 * 256);
    float4* xs = (float4*)&xr[0][0];
    #pragma unroll
    for (int s = 0; s < 4; ++s) xs[s * 256 + t] = xg[s * 256 + t];
    __syncthreads();
    int w = t >> 6, l = t & 63;
    {
        float bb = b1[l];
        float a0 = bb, a1 = bb, a2 = bb, a3 = bb;
        const float* x0 = xr[w * 4 + 0];
        const float* x1 = xr[w * 4 + 1];
        const float* x2 = xr[w * 4 + 2];
        const float* x3 = xr[w * 4 + 3];
        for (int c = 0; c < 256; ++c) {
            float wv = W1[c * 64 + l];
            a0 = fmaf(x0[c], wv, a0);
            a1 = fmaf(x1[c], wv, a1);
            a2 = fmaf(x2[c], wv, a2);
            a3 = fmaf(x3[c], wv, a3);
        }
        ebuf[w * 4 + 0][l] = fmaxf(a0, 0.f);
        ebuf[w * 4 + 1][l] = fmaxf(a1, 0.f);
        ebuf[w * 4 + 2][l] = fmaxf(a2, 0.f);
        ebuf[w * 4 + 3][l] = fmaxf(a3, 0.f);
    }
    __syncthreads();
    int rr = t >> 4, cc = t & 15;
    if (cc < 9) {
        float acc = b2[cc];
        for (int j = 0; j < 64; ++j)
            acc = fmaf(ebuf[rr][j], W2[j * 9 + cc], acc);
        lg[rr][cc] = acc;
    }
    __syncthreads();
    if (cc == 0) {
        float best = lg[rr][0];
        int bi = 0;
        #pragma unroll
        for (int j = 1; j < 9; ++j)
            if (lg[rr][j] > best) { best = lg[rr][j]; bi = j; }
        kint[r0 + rr] = bi;
        degf[r0 + rr] = (float)bi;
    }
}

// ---------------- gather: Z(bf16) = [deg*feat | nbr_sum - deg*feat] ----------------
template<int REMAP, int BF16IN>
__global__ __launch_bounds__(256) void gather_kernel(const void* __restrict__ featv,
        const int* __restrict__ nbr, const int* __restrict__ kint_,
        const float* __restrict__ degf, __bf16* __restrict__ Z) {
    int g = threadIdx.x >> 6, lane = threadIdx.x & 63;
    int r = blockIdx.x * 4 + g;
    int b = r / NPT, i = r - b * NPT;
    int fb = REMAP ? src_batch(b) : b;
    float sv[4];
    if constexpr (BF16IN) {
        const __bf16* feat = (const __bf16*)featv;
        bf16x4 v = *(const bf16x4*)(feat + ((size_t)fb * NPT + i) * CH + lane * 4);
        #pragma unroll
        for (int j = 0; j < 4; ++j) sv[j] = (float)v[j];
    } else {
        const float* feat = (const float*)featv;
        float4 v = *(const float4*)(feat + ((size_t)fb * NPT + i) * CH + lane * 4);
        sv[0] = v.x; sv[1] = v.y; sv[2] = v.z; sv[3] = v.w;
    }
    float s[4] = {0.f, 0.f, 0.f, 0.f};
    int kk = kint_[r];
    const int* nb = nbr + (size_t)r * KNB;
    for (int tt = 0; tt < kk; ++tt) {
        int m = nb[tt];
        if constexpr (BF16IN) {
            const __bf16* feat = (const __bf16*)featv;
            bf16x4 v = *(const bf16x4*)(feat + ((size_t)fb * NPT + m) * CH + lane * 4);
            #pragma unroll
            for (int j = 0; j < 4; ++j) s[j] += (float)v[j];
        } else {
            const float* feat = (const float*)featv;
            float4 v = *(const float4*)(feat + ((size_t)fb * NPT + m) * CH + lane * 4);
            s[0] += v.x; s[1] += v.y; s[2] += v.z; s[3] += v.w;
        }
    }
    float dg = degf[r];
    bf16x4 av, dv;
    #pragma unroll
    for (int j = 0; j < 4; ++j) {
        float a = dg * sv[j];
        av[j] = (__bf16)a;
        dv[j] = (__bf16)(s[j] - a);
    }
    *(bf16x4*)(Z + (size_t)r * 512 + lane * 4) = av;
    *(bf16x4*)(Z + (size_t)r * 512 + 256 + lane * 4) = dv;
}

// ---------------- bf16 MFMA GEMM: C = op(A @ W + [deg*]bias) ----------------
// FLAGS: 1=RELU, 2=DEG-scaled bias, 4=bf16 output (else f32).
template<int FLAGS, int CONCAT>
__global__ __launch_bounds__(256) void mfma_gemm(
    const __bf16* __restrict__ A0, const __bf16* __restrict__ A1,
    const __bf16* __restrict__ WT, const float* __restrict__ bias,
    const float* __restrict__ degf, float* __restrict__ Cf,
    __bf16* __restrict__ Cb, int K, int N) {
    __shared__ __attribute__((aligned(16))) __bf16 As[128 * 64];
    __shared__ __attribute__((aligned(16))) __bf16 Bs[128 * 64];
    int t = threadIdx.x, w = t >> 6, l = t & 63;
    int r0 = blockIdx.y * 128, c0 = blockIdx.x * 128;
    int lr = l & 15, lg = l >> 4;
    int wr = (w >> 1) * 64, wc = (w & 1) * 64;
    f32x4 acc[4][4] = {};
    for (int k0 = 0; k0 < K; k0 += 64) {
        const __bf16* Ab = A0;
        int kk = k0;
        size_t KA = CONCAT ? 512 : (size_t)K;
        if (CONCAT && k0 >= 512) { Ab = A1; kk = k0 - 512; }
        #pragma unroll
        for (int i = 0; i < 4; ++i) {
            int row = (w * 4 + i) * 8 + (l >> 3);
            int c8 = l & 7;
            gload_lds16(Ab + (size_t)(r0 + row) * KA + kk + c8 * 8,
                        As + (w * 4 + i) * 512);
            gload_lds16(WT + (size_t)(c0 + row) * K + k0 + c8 * 8,
                        Bs + (w * 4 + i) * 512);
        }
        asm volatile("s_waitcnt vmcnt(0)" ::: "memory");
        __syncthreads();
        #pragma unroll
        for (int ks = 0; ks < 2; ++ks) {
            bf16x8 af[4], bfr[4];
            #pragma unroll
            for (int mi = 0; mi < 4; ++mi)
                af[mi] = *(const bf16x8*)(As + (wr + mi * 16 + lr) * 64 + ks * 32 + lg * 8);
            #pragma unroll
            for (int ni = 0; ni < 4; ++ni)
                bfr[ni] = *(const bf16x8*)(Bs + (wc + ni * 16 + lr) * 64 + ks * 32 + lg * 8);
            #pragma unroll
            for (int mi = 0; mi < 4; ++mi)
                #pragma unroll
                for (int ni = 0; ni < 4; ++ni)
                    acc[mi][ni] = __builtin_amdgcn_mfma_f32_16x16x32_bf16(
                        af[mi], bfr[ni], acc[mi][ni], 0, 0, 0);
        }
        __syncthreads();
    }
    #pragma unroll
    for (int mi = 0; mi < 4; ++mi) {
        #pragma unroll
        for (int r = 0; r < 4; ++r) {
            int row = r0 + wr + mi * 16 + lg * 4 + r;
            float dsc = 1.f;
            if constexpr ((FLAGS & 2) != 0) dsc = degf[row];
            #pragma unroll
            for (int ni = 0; ni < 4; ++ni) {
                int col = c0 + wc + ni * 16 + lr;
                float v = acc[mi][ni][r] + dsc * bias[col];
                if constexpr ((FLAGS & 1) != 0) v = fmaxf(v, 0.f);
                if constexpr ((FLAGS & 4) != 0)
                    Cb[(size_t)row * N + col] = (__bf16)v;
                else
                    Cf[(size_t)row * N + col] = v;
            }
        }
    }
}

// ---------------- weight transpose + f32->bf16: WT[n][k] = W[k][n] ----------------
__global__ __launch_bounds__(256) void transpose_w(const float* __restrict__ W,
        __bf16* __restrict__ WT, int K, int N) {
    __shared__ float tile[64][65];
    int k0 = blockIdx.x * 64, n0 = blockIdx.y * 64;
    int t = threadIdx.x;
    #pragma unroll
    for (int s = 0; s < 16; ++s) {
        int idx = s * 256 + t;
        int kk = idx >> 6, nn = idx & 63;
        tile[kk][nn] = W[(size_t)(k0 + kk) * N + n0 + nn];
    }
    __syncthreads();
    #pragma unroll
    for (int s = 0; s < 16; ++s) {
        int idx = s * 256 + t;
        int nn = idx >> 6, kk = idx & 63;
        WT[(size_t)(n0 + nn) * K + k0 + kk] = (__bf16)tile[kk][nn];
    }
}

// ---------------- flat f32 -> bf16 ----------------
__global__ __launch_bounds__(256) void convert_bf16(const float* __restrict__ src,
                                                    __bf16* __restrict__ dst) {
    int idx = blockIdx.x * 256 + threadIdx.x;
    float4 v = *(const float4*)(src + (size_t)idx * 4);
    bf16x4 o;
    o[0] = (__bf16)v.x; o[1] = (__bf16)v.y; o[2] = (__bf16)v.z; o[3] = (__bf16)v.w;
    *(bf16x4*)(dst + (size_t)idx * 4) = o;
}

// ---------------- fused mix: FUSED(bf16) = wgt*XAGG + (1-wgt)*YAGG ----------------
__global__ __launch_bounds__(256) void fuse_mix(const float* __restrict__ XA,
        const float* __restrict__ YA, const float* __restrict__ wgt,
        __bf16* __restrict__ F) {
    int idx = blockIdx.x * 256 + threadIdx.x;
    size_t e0 = (size_t)idx * 4;
    int r = (int)(e0 >> 9);
    float wv = wgt[r];
    float4 xv = *(const float4*)(XA + e0);
    float4 yv = *(const float4*)(YA + e0);
    bf16x4 o;
    o[0] = (__bf16)(wv * xv.x + (1.f - wv) * yv.x);
    o[1] = (__bf16)(wv * xv.y + (1.f - wv) * yv.y);
    o[2] = (__bf16)(wv * xv.z + (1.f - wv) * yv.z);
    o[3] = (__bf16)(wv * xv.w + (1.f - wv) * yv.w);
    *(bf16x4*)(F + e0) = o;
}

// ---------------- attention scores (f32) ----------------
__global__ __launch_bounds__(256) void scores_kernel(const float* __restrict__ xagg,
        const float* __restrict__ yagg, const float* __restrict__ aw,
        const float* __restrict__ ab, float* __restrict__ scores) {
    int g = threadIdx.x >> 6, lane = threadIdx.x & 63;
    int r = blockIdx.x * 4 + g;
    float acc = 0.f;
    #pragma unroll
    for (int s = 0; s < 8; ++s) {
        int c = lane + 64 * s;
        acc = fmaf(xagg[(size_t)r * 512 + c], aw[c], acc);
        acc = fmaf(yagg[(size_t)r * 512 + c], aw[512 + c], acc);
    }
    #pragma unroll
    for (int off = 32; off; off >>= 1) acc += __shfl_xor(acc, off, 64);
    if (lane == 0) scores[r] = acc + ab[0];
}

// ---------------- global softmax ----------------
__global__ __launch_bounds__(1024) void softmax_kernel(const float* __restrict__ scores,
                                                       float* __restrict__ wgt) {
    __shared__ float red[1024];
    int t = threadIdx.x;
    float mx = -3.402823466e+38f;
    for (int i = t; i < ROWS; i += 1024) mx = fmaxf(mx, scores[i]);
    red[t] = mx; __syncthreads();
    for (int off = 512; off; off >>= 1) {
        if (t < off) red[t] = fmaxf(red[t], red[t + off]);
        __syncthreads();
    }
    mx = red[0]; __syncthreads();
    float sm = 0.f;
    for (int i = t; i < ROWS; i += 1024) sm += expf(scores[i] - mx);
    red[t] = sm; __syncthreads();
    for (int off = 512; off; off >>= 1) {
        if (t < off) red[t] += red[t + off];
        __syncthreads();
    }
    float denom = red[0];
    for (int i = t; i < ROWS; i += 1024) wgt[i] = expf(scores[i] - mx) / denom;
}

// ---------------- final transpose: UPD[r][c] -> out[b][c][i] ----------------
__global__ __launch_bounds__(256) void transpose_out(const float* __restrict__ UPD,
                                                     float* __restrict__ out) {
    __shared__ float tile[64][65];
    int r0 = blockIdx.x * 64, c0 = blockIdx.y * 64;
    int t = threadIdx.x;
    #pragma unroll
    for (int s = 0; s < 16; ++s) {
        int idx = s * 256 + t;
        int rr = idx >> 6, cc = idx & 63;
        tile[rr][cc] = UPD[(size_t)(r0 + rr) * 512 + c0 + cc];
    }
    __syncthreads();
    #pragma unroll
    for (int s = 0; s < 16; ++s) {
        int idx = s * 256 + t;
        int cc = idx >> 6, rr = idx & 63;
        int r = r0 + rr, c = c0 + cc;
        int b = r / NPT, i = r - b * NPT;
        out[((size_t)b * 512 + c) * NPT + i] = tile[rr][cc];
    }
}

extern "C" void kernel_launch(void* const* d_in, const int* in_sizes, int n_in,
                              void* d_out, int out_size, void* d_ws, size_t ws_size,
                              hipStream_t stream) {
    (void)in_sizes; (void)n_in; (void)out_size; (void)ws_size;
    const float* x       = (const float*)d_in[0];
    const float* fc1_w   = (const float*)d_in[1];
    const float* fc1_b   = (const float*)d_in[2];
    const float* fc2_w   = (const float*)d_in[3];
    const float* fc2_b   = (const float*)d_in[4];
    const float* fce_w   = (const float*)d_in[5];
    const float* fce_b   = (const float*)d_in[6];
    const float* inout_w = (const float*)d_in[7];
    const float* inout_b = (const float*)d_in[8];
    const float* attn_w  = (const float*)d_in[9];
    const float* attn_b  = (const float*)d_in[10];
    const float* upd_w   = (const float*)d_in[11];
    const float* upd_b   = (const float*)d_in[12];
    const float* kp_w    = (const float*)d_in[13];
    const float* kp_b    = (const float*)d_in[14];
    const float* enc_w   = (const float*)d_in[15];
    const float* enc_b   = (const float*)d_in[16];
    const float* mu_w    = (const float*)d_in[17];
    const float* mu_b    = (const float*)d_in[18];
    const float* dec_w   = (const float*)d_in[19];
    const float* dec_b   = (const float*)d_in[20];
    float* out = (float*)d_out;

    char* base = (char*)d_ws;
    size_t o = 0;
    auto alloc = [&](size_t bytes) -> void* {
        void* p = base + o;
        o += (bytes + 255) & ~(size_t)255;
        return p;
    };
    float* qs     = (float*)alloc(ROWS * 4);
    float* degf   = (float*)alloc(ROWS * 4);
    float* scores = (float*)alloc(ROWS * 4);
    float* wgt    = (float*)alloc(ROWS * 4);
    int*   kint   = (int*)  alloc(ROWS * 4);
    float* W1     = (float*)alloc(256 * 64 * 4);
    float* b1     = (float*)alloc(64 * 4);
    float* W2     = (float*)alloc(64 * 9 * 4);
    float* b2     = (float*)alloc(9 * 4);
    size_t regionA = o;  // D + nbr + Z overlaid by UPD later (all dead by then)
    float* D      = (float*)alloc((size_t)128 * NPT * NPT * 4);   // 19.66 MB
    int*   nbr    = (int*)  alloc((size_t)128 * NPT * KNB * 4);   //  0.80 MB
    __bf16* Z     = (__bf16*)alloc((size_t)ROWS * 512 * 2);       // 12.85 MB
    __bf16* H1    = (__bf16*)alloc((size_t)ROWS * 256 * 2);
    __bf16* H2    = (__bf16*)alloc((size_t)ROWS * 256 * 2);
    __bf16* XB    = (__bf16*)alloc((size_t)ROWS * 256 * 2);
    float* XAGG   = (float*)alloc((size_t)ROWS * 512 * 4);        // 25.69 MB
    float* YAGG   = (float*)alloc((size_t)ROWS * 512 * 4);
    __bf16* XIN   = (__bf16*)alloc((size_t)ROWS * 512 * 2);
    __bf16* FUSED = (__bf16*)alloc((size_t)ROWS * 512 * 2);
    __bf16* fc1t  = (__bf16*)alloc((size_t)512 * 256 * 2);
    __bf16* fc2t  = (__bf16*)alloc((size_t)512 * 256 * 2);
    __bf16* fcet  = (__bf16*)alloc((size_t)256 * 512 * 2);
    __bf16* inoutT= (__bf16*)alloc((size_t)256 * 512 * 2);
    __bf16* updT  = (__bf16*)alloc((size_t)1024 * 512 * 2);
    float* UPD    = (float*)(base + regionA);  // 25.69 MB, aliases D+nbr+Z
    // XSPH/XSPL (8.39 MB each) alias XAGG (25.69 MB): dead before fce writes XAGG.
    _Float16* XSPH = (_Float16*)XAGG;
    _Float16* XSPL = XSPH + (size_t)64 * 256 * 256;

    const int* nbrx = nbr;
    const int* nbry = nbr + (size_t)64 * NPT * KNB;

    // ---- weight prep: transposes, bf16 conversion, composed k-predictor ----
    transpose_w<<<dim3(8, 4),  256, 0, stream>>>(fc1_w,   fc1t,   512, 256);
    transpose_w<<<dim3(8, 4),  256, 0, stream>>>(fc2_w,   fc2t,   512, 256);
    transpose_w<<<dim3(4, 8),  256, 0, stream>>>(fce_w,   fcet,   256, 512);
    transpose_w<<<dim3(4, 8),  256, 0, stream>>>(inout_w, inoutT, 256, 512);
    transpose_w<<<dim3(16, 8), 256, 0, stream>>>(upd_w,   updT,   1024, 512);
    convert_bf16<<<3136, 256, 0, stream>>>(x, XB);
    compose_w1<<<65, 256, 0, stream>>>(kp_w, kp_b, enc_w, enc_b, W1, b1);
    compose_w2<<<3, 256, 0, stream>>>(mu_w, mu_b, dec_w, dec_b, W2, b2);

    // ---- KNN (f16-split MFMA gram, f32-quality) + collapsed k-predictor ----
    qs_kernel<<<64, 256, 0, stream>>>(x, qs);
    trans_split<<<dim3(4, 4, 64), 256, 0, stream>>>(x, XSPH, XSPL);
    gram_mfma<<<dim3(2, 2, 128), 256, 0, stream>>>(XSPH, XSPL, D);
    topk_kernel<<<(128 * NPT) / 4, 256, 0, stream>>>(D, qs, nbr);
    kint2_kernel<<<ROWS / 16, 256, 0, stream>>>(x, W1, b1, W2, b2, kint, degf);

    // ---- x branch ----
    gather_kernel<0, 0><<<ROWS / 4, 256, 0, stream>>>(x, nbrx, kint, degf, Z);
    mfma_gemm<7, 0><<<dim3(2, 98), 256, 0, stream>>>(
        Z, nullptr, fc1t, fc1_b, degf, nullptr, H1, 512, 256);
    gather_kernel<0, 1><<<ROWS / 4, 256, 0, stream>>>(H1, nbrx, kint, degf, Z);
    mfma_gemm<6, 0><<<dim3(2, 98), 256, 0, stream>>>(
        Z, nullptr, fc2t, fc2_b, degf, nullptr, H2, 512, 256);
    mfma_gemm<0, 0><<<dim3(4, 98), 256, 0, stream>>>(
        H2, nullptr, fcet, fce_b, nullptr, XAGG, nullptr, 256, 512);

    // ---- y branch ----
    gather_kernel<1, 0><<<ROWS / 4, 256, 0, stream>>>(x, nbry, kint, degf, Z);
    mfma_gemm<7, 0><<<dim3(2, 98), 256, 0, stream>>>(
        Z, nullptr, fc1t, fc1_b, degf, nullptr, H1, 512, 256);
    gather_kernel<0, 1><<<ROWS / 4, 256, 0, stream>>>(H1, nbry, kint, degf, Z);
    mfma_gemm<6, 0><<<dim3(2, 98), 256, 0, stream>>>(
        Z, nullptr, fc2t, fc2_b, degf, nullptr, H2, 512, 256);
    mfma_gemm<0, 0><<<dim3(4, 98), 256, 0, stream>>>(
        H2, nullptr, fcet, fce_b, nullptr, YAGG, nullptr, 256, 512);

    // ---- attention fusion ----
    scores_kernel<<<ROWS / 4, 256, 0, stream>>>(XAGG, YAGG, attn_w, attn_b, scores);
    softmax_kernel<<<1, 1024, 0, stream>>>(scores, wgt);
    fuse_mix<<<6272, 256, 0, stream>>>(XAGG, YAGG, wgt, FUSED);

    // ---- xin + final update GEMM + output transpose ----
    mfma_gemm<4, 0><<<dim3(4, 98), 256, 0, stream>>>(
        XB, nullptr, inoutT, inout_b, nullptr, nullptr, XIN, 256, 512);
    mfma_gemm<1, 1><<<dim3(4, 98), 256, 0, stream>>>(
        XIN, FUSED, updT, upd_b, nullptr, UPD, nullptr, 1024, 512);
    transpose_out<<<dim3(196, 8), 256, 0, stream>>>(UPD, out);
}

// Round 5
// 275.993 us; speedup vs baseline: 3.4098x; 1.2138x over previous
//
#include <hip/hip_runtime.h>
#include <cstddef>
#include <cstdint>

constexpr int BATCH = 64;
constexpr int CH    = 256;
constexpr int NPT   = 196;
constexpr int ROWS  = BATCH * NPT;   // 12544
constexpr int BSTRIDE = CH * NPT;    // 50176
constexpr int KNB   = 8;             // position 8 (9th) is never valid: k_int <= 8

typedef __bf16 bf16x8 __attribute__((ext_vector_type(8)));
typedef __bf16 bf16x4 __attribute__((ext_vector_type(4)));
typedef _Float16 f16x8 __attribute__((ext_vector_type(8)));
typedef float  f32x4  __attribute__((ext_vector_type(4)));

__device__ __forceinline__ int src_batch(int b) {
    return (b & ~15) | ((b + 1) & 15);
}

__device__ __forceinline__ void gload_lds16(const void* g, void* l) {
    __builtin_amdgcn_global_load_lds(
        (const __attribute__((address_space(1))) void*)g,
        (__attribute__((address_space(3))) void*)l, 16, 0, 0);
}

// ---------------- qs: per-point squared norm (f32-exact) ----------------
__global__ __launch_bounds__(256) void qs_kernel(const float* __restrict__ x,
                                                 float* __restrict__ qs) {
    int b = blockIdx.x;
    int m = threadIdx.x;
    if (m >= NPT) return;
    const float* xb = x + (size_t)b * BSTRIDE;
    float acc = 0.f;
    for (int c = 0; c < CH; ++c) {
        float v = xb[c * NPT + m];
        acc = fmaf(v, v, acc);
    }
    qs[b * NPT + m] = acc;
}

// ---------------- transpose + f16 hi/lo split: x[b][c][m] -> XH/XL[b][m][c] ----------------
__global__ __launch_bounds__(256) void trans_split(const float* __restrict__ x,
        _Float16* __restrict__ XH, _Float16* __restrict__ XL) {
    __shared__ float tile[64][65];
    int b = blockIdx.z;
    int m0 = blockIdx.x * 64, c0 = blockIdx.y * 64;
    int t = threadIdx.x;
    const float* xb = x + (size_t)b * BSTRIDE;
    #pragma unroll
    for (int s = 0; s < 16; ++s) {
        int idx = s * 256 + t;
        int cc = idx >> 6, mm = idx & 63;
        int m = m0 + mm;
        tile[cc][mm] = (m < NPT) ? xb[(size_t)(c0 + cc) * NPT + m] : 0.f;
    }
    __syncthreads();
    #pragma unroll
    for (int s = 0; s < 16; ++s) {
        int idx = s * 256 + t;
        int mm = idx >> 6, cc = idx & 63;
        float v = tile[cc][mm];
        _Float16 h = (_Float16)v;
        size_t off = ((size_t)b * 256 + (m0 + mm)) * 256 + c0 + cc;
        XH[off] = h;
        XL[off] = (_Float16)(v - (float)h);
    }
}

// ---------------- Gram via f16-split MFMA: D = Ah*Bh + Ah*Bl + Al*Bh ----------------
__global__ __launch_bounds__(256) void gram_mfma(const _Float16* __restrict__ XH,
        const _Float16* __restrict__ XL, float* __restrict__ D) {
    __shared__ __attribute__((aligned(16))) _Float16 Ah[128 * 64];
    __shared__ __attribute__((aligned(16))) _Float16 Al[128 * 64];
    __shared__ __attribute__((aligned(16))) _Float16 Bh[128 * 64];
    __shared__ __attribute__((aligned(16))) _Float16 Bl[128 * 64];
    int job = blockIdx.z;
    int qb = (job < 64) ? job : job - 64;
    int kb = (job < 64) ? qb : src_batch(qb);
    int t = threadIdx.x, w = t >> 6, l = t & 63;
    int r0 = blockIdx.y * 128, c0 = blockIdx.x * 128;
    int lr = l & 15, lg = l >> 4;
    int wr = (w >> 1) * 64, wc = (w & 1) * 64;
    const _Float16* qh = XH + (size_t)qb * 65536;
    const _Float16* ql = XL + (size_t)qb * 65536;
    const _Float16* kh = XH + (size_t)kb * 65536;
    const _Float16* kl = XL + (size_t)kb * 65536;
    f32x4 acc[4][4] = {};
    for (int k0 = 0; k0 < 256; k0 += 64) {
        #pragma unroll
        for (int i = 0; i < 4; ++i) {
            int row = (w * 4 + i) * 8 + (l >> 3);
            int c8 = l & 7;
            size_t goA = (size_t)(r0 + row) * 256 + k0 + c8 * 8;
            size_t goB = (size_t)(c0 + row) * 256 + k0 + c8 * 8;
            gload_lds16(qh + goA, Ah + (w * 4 + i) * 512);
            gload_lds16(ql + goA, Al + (w * 4 + i) * 512);
            gload_lds16(kh + goB, Bh + (w * 4 + i) * 512);
            gload_lds16(kl + goB, Bl + (w * 4 + i) * 512);
        }
        asm volatile("s_waitcnt vmcnt(0)" ::: "memory");
        __syncthreads();
        #pragma unroll
        for (int ks = 0; ks < 2; ++ks) {
            f16x8 ah[4], al[4], bh[4], bl[4];
            #pragma unroll
            for (int mi = 0; mi < 4; ++mi) {
                ah[mi] = *(const f16x8*)(Ah + (wr + mi * 16 + lr) * 64 + ks * 32 + lg * 8);
                al[mi] = *(const f16x8*)(Al + (wr + mi * 16 + lr) * 64 + ks * 32 + lg * 8);
            }
            #pragma unroll
            for (int ni = 0; ni < 4; ++ni) {
                bh[ni] = *(const f16x8*)(Bh + (wc + ni * 16 + lr) * 64 + ks * 32 + lg * 8);
                bl[ni] = *(const f16x8*)(Bl + (wc + ni * 16 + lr) * 64 + ks * 32 + lg * 8);
            }
            #pragma unroll
            for (int mi = 0; mi < 4; ++mi)
                #pragma unroll
                for (int ni = 0; ni < 4; ++ni) {
                    acc[mi][ni] = __builtin_amdgcn_mfma_f32_16x16x32_f16(
                        ah[mi], bh[ni], acc[mi][ni], 0, 0, 0);
                    acc[mi][ni] = __builtin_amdgcn_mfma_f32_16x16x32_f16(
                        ah[mi], bl[ni], acc[mi][ni], 0, 0, 0);
                    acc[mi][ni] = __builtin_amdgcn_mfma_f32_16x16x32_f16(
                        al[mi], bh[ni], acc[mi][ni], 0, 0, 0);
                }
        }
        __syncthreads();
    }
    #pragma unroll
    for (int mi = 0; mi < 4; ++mi) {
        #pragma unroll
        for (int r = 0; r < 4; ++r) {
            int gi = r0 + wr + mi * 16 + lg * 4 + r;
            if (gi >= NPT) continue;
            #pragma unroll
            for (int ni = 0; ni < 4; ++ni) {
                int gj = c0 + wc + ni * 16 + lr;
                if (gj < NPT)
                    D[(size_t)job * (NPT * NPT) + (size_t)gi * NPT + gj] =
                        acc[mi][ni][r];
            }
        }
    }
}

// ---------------- top-8 selection ----------------
__global__ __launch_bounds__(256) void topk_kernel(const float* __restrict__ D,
                                                   const float* __restrict__ qs,
                                                   int* __restrict__ nbr) {
    int wid = threadIdx.x >> 6;
    int lane = threadIdx.x & 63;
    int rowid = blockIdx.x * 4 + wid;
    int job = rowid / NPT;
    int i = rowid - job * NPT;
    int qb = (job < 64) ? job : job - 64;
    int kb = (job < 64) ? qb : src_batch(qb);
    const float* drow = D + (size_t)job * (NPT * NPT) + (size_t)i * NPT;
    float qsi = qs[qb * NPT + i];
    const float* ksr = qs + kb * NPT;
    float dist[4];
    #pragma unroll
    for (int s = 0; s < 4; ++s) {
        int m = lane + 64 * s;
        dist[s] = (m < NPT) ? (qsi - 2.f * drow[m] + ksr[m])
                            : __uint_as_float(0x7f800000u);
    }
    for (int it = 0; it < KNB; ++it) {
        unsigned long long best = ~0ull;
        #pragma unroll
        for (int s = 0; s < 4; ++s) {
            unsigned u = __float_as_uint(dist[s]);
            u = (u & 0x80000000u) ? ~u : (u | 0x80000000u);
            unsigned long long key = ((unsigned long long)u << 32) |
                                     (unsigned)(lane + 64 * s);
            if (key < best) best = key;
        }
        #pragma unroll
        for (int off = 32; off; off >>= 1) {
            unsigned long long o = __shfl_xor(best, off, 64);
            if (o < best) best = o;
        }
        int widx = (int)(best & 0xffffffffu);
        if (lane == (widx & 63)) dist[widx >> 6] = __uint_as_float(0x7f800000u);
        if (lane == 0) nbr[(size_t)rowid * KNB + it] = widx;
    }
}

// ---------------- compose W1/b1 and W2/b2 (f64 accum) in one dispatch ----------------
__global__ __launch_bounds__(256) void compose_all(const float* __restrict__ kp_w,
        const float* __restrict__ kp_b, const float* __restrict__ enc_w,
        const float* __restrict__ enc_b, const float* __restrict__ mu_w,
        const float* __restrict__ mu_b, const float* __restrict__ dec_w,
        const float* __restrict__ dec_b, float* __restrict__ W1,
        float* __restrict__ b1, float* __restrict__ W2, float* __restrict__ b2) {
    int bid = blockIdx.x;
    if (bid < 64) {
        int i = bid * 4 + (threadIdx.x >> 6);
        int j = threadIdx.x & 63;
        double acc = 0.0;
        for (int k = 0; k < 500; ++k)
            acc += (double)kp_w[(size_t)i * 500 + k] * (double)enc_w[(size_t)k * 64 + j];
        W1[i * 64 + j] = (float)acc;
    } else if (bid == 64) {
        int j = threadIdx.x;
        if (j < 64) {
            double acc = (double)enc_b[j];
            for (int k = 0; k < 500; ++k)
                acc += (double)kp_b[k] * (double)enc_w[(size_t)k * 64 + j];
            b1[j] = (float)acc;
        }
    } else {
        int t = (bid - 65) * 256 + threadIdx.x;
        if (t < 576) {
            int i = t / 9, j = t - (t / 9) * 9;
            double acc = 0.0;
            for (int k = 0; k < 32; ++k)
                acc += (double)mu_w[(size_t)i * 32 + k] * (double)dec_w[(size_t)k * 9 + j];
            W2[t] = (float)acc;
        } else if (t < 585) {
            int j = t - 576;
            double acc = (double)dec_b[j];
            for (int k = 0; k < 32; ++k)
                acc += (double)mu_b[k] * (double)dec_w[(size_t)k * 9 + j];
            b2[j] = (float)acc;
        }
    }
}

// ---------------- collapsed k-predictor ----------------
__global__ __launch_bounds__(256) void kint2_kernel(const float* __restrict__ x,
    const float* __restrict__ W1, const float* __restrict__ b1,
    const float* __restrict__ W2, const float* __restrict__ b2,
    int* __restrict__ kint, float* __restrict__ degf) {
    __shared__ __attribute__((aligned(16))) float xr[16][256];
    __shared__ float ebuf[16][64];
    __shared__ float lg[16][9];
    int t = threadIdx.x;
    int r0 = blockIdx.x * 16;
    const float4* xg = (const float4*)(x + (size_t)r0 * 256);
    float4* xs = (float4*)&xr[0][0];
    #pragma unroll
    for (int s = 0; s < 4; ++s) xs[s * 256 + t] = xg[s * 256 + t];
    __syncthreads();
    int w = t >> 6, l = t & 63;
    {
        float bb = b1[l];
        float a0 = bb, a1 = bb, a2 = bb, a3 = bb;
        const float* x0 = xr[w * 4 + 0];
        const float* x1 = xr[w * 4 + 1];
        const float* x2 = xr[w * 4 + 2];
        const float* x3 = xr[w * 4 + 3];
        for (int c = 0; c < 256; ++c) {
            float wv = W1[c * 64 + l];
            a0 = fmaf(x0[c], wv, a0);
            a1 = fmaf(x1[c], wv, a1);
            a2 = fmaf(x2[c], wv, a2);
            a3 = fmaf(x3[c], wv, a3);
        }
        ebuf[w * 4 + 0][l] = fmaxf(a0, 0.f);
        ebuf[w * 4 + 1][l] = fmaxf(a1, 0.f);
        ebuf[w * 4 + 2][l] = fmaxf(a2, 0.f);
        ebuf[w * 4 + 3][l] = fmaxf(a3, 0.f);
    }
    __syncthreads();
    int rr = t >> 4, cc = t & 15;
    if (cc < 9) {
        float acc = b2[cc];
        for (int j = 0; j < 64; ++j)
            acc = fmaf(ebuf[rr][j], W2[j * 9 + cc], acc);
        lg[rr][cc] = acc;
    }
    __syncthreads();
    if (cc == 0) {
        float best = lg[rr][0];
        int bi = 0;
        #pragma unroll
        for (int j = 1; j < 9; ++j)
            if (lg[rr][j] > best) { best = lg[rr][j]; bi = j; }
        kint[r0 + rr] = bi;
        degf[r0 + rr] = (float)bi;
    }
}

// ---------------- merged stage-1 gather (x f32, both branches) ----------------
__global__ __launch_bounds__(256) void gatherS1(const float* __restrict__ x,
        const int* __restrict__ nbr, const int* __restrict__ kint_,
        const float* __restrict__ degf, __bf16* __restrict__ Z) {
    int g = threadIdx.x >> 6, lane = threadIdx.x & 63;
    int r = blockIdx.x * 4 + g;               // 0..2*ROWS
    int branch = (r >= ROWS);
    int rr = r - branch * ROWS;
    int b = rr / NPT, i = rr - b * NPT;
    int fb = branch ? src_batch(b) : b;
    const int* nb = nbr + (size_t)branch * ((size_t)ROWS * KNB) + (size_t)rr * KNB;
    float4 sv = *(const float4*)(x + ((size_t)fb * NPT + i) * CH + lane * 4);
    float s0 = 0.f, s1 = 0.f, s2 = 0.f, s3 = 0.f;
    int kk = kint_[rr];
    for (int tt = 0; tt < kk; ++tt) {
        int m = nb[tt];
        float4 v = *(const float4*)(x + ((size_t)fb * NPT + m) * CH + lane * 4);
        s0 += v.x; s1 += v.y; s2 += v.z; s3 += v.w;
    }
    float dg = degf[rr];
    float a0 = dg * sv.x, a1 = dg * sv.y, a2 = dg * sv.z, a3 = dg * sv.w;
    bf16x4 av, dv;
    av[0] = (__bf16)a0; av[1] = (__bf16)a1; av[2] = (__bf16)a2; av[3] = (__bf16)a3;
    dv[0] = (__bf16)(s0 - a0); dv[1] = (__bf16)(s1 - a1);
    dv[2] = (__bf16)(s2 - a2); dv[3] = (__bf16)(s3 - a3);
    *(bf16x4*)(Z + (size_t)r * 512 + lane * 4) = av;
    *(bf16x4*)(Z + (size_t)r * 512 + 256 + lane * 4) = dv;
}

// ---------------- merged stage-2 gather (H1 bf16 merged 2*ROWS) ----------------
__global__ __launch_bounds__(256) void gatherS2(const __bf16* __restrict__ H1,
        const int* __restrict__ nbr, const int* __restrict__ kint_,
        const float* __restrict__ degf, __bf16* __restrict__ Z) {
    int g = threadIdx.x >> 6, lane = threadIdx.x & 63;
    int r = blockIdx.x * 4 + g;
    int branch = (r >= ROWS);
    int rr = r - branch * ROWS;
    int b = rr / NPT;
    const int* nb = nbr + (size_t)branch * ((size_t)ROWS * KNB) + (size_t)rr * KNB;
    size_t mbase = (size_t)branch * ROWS + (size_t)b * NPT;
    bf16x4 v = *(const bf16x4*)(H1 + (size_t)r * CH + lane * 4);
    float sv0 = (float)v[0], sv1 = (float)v[1], sv2 = (float)v[2], sv3 = (float)v[3];
    float s0 = 0.f, s1 = 0.f, s2 = 0.f, s3 = 0.f;
    int kk = kint_[rr];
    for (int tt = 0; tt < kk; ++tt) {
        int m = nb[tt];
        bf16x4 nv = *(const bf16x4*)(H1 + (mbase + m) * CH + lane * 4);
        s0 += (float)nv[0]; s1 += (float)nv[1]; s2 += (float)nv[2]; s3 += (float)nv[3];
    }
    float dg = degf[rr];
    float a0 = dg * sv0, a1 = dg * sv1, a2 = dg * sv2, a3 = dg * sv3;
    bf16x4 av, dv;
    av[0] = (__bf16)a0; av[1] = (__bf16)a1; av[2] = (__bf16)a2; av[3] = (__bf16)a3;
    dv[0] = (__bf16)(s0 - a0); dv[1] = (__bf16)(s1 - a1);
    dv[2] = (__bf16)(s2 - a2); dv[3] = (__bf16)(s3 - a3);
    *(bf16x4*)(Z + (size_t)r * 512 + lane * 4) = av;
    *(bf16x4*)(Z + (size_t)r * 512 + 256 + lane * 4) = dv;
}

// ---------------- bf16 MFMA GEMM ----------------
// FLAGS: 1=RELU, 2=DEG bias (index mod ROWS), 4=bf16 out, 8=transposed out[b][c][i].
template<int FLAGS, int CONCAT>
__global__ __launch_bounds__(256) void mfma_gemm(
    const __bf16* __restrict__ A0, const __bf16* __restrict__ A1,
    const __bf16* __restrict__ WT, const float* __restrict__ bias,
    const float* __restrict__ degf, float* __restrict__ Cf,
    __bf16* __restrict__ Cb, int K, int N) {
    constexpr int SMEMB = (FLAGS & 8) ? (128 * 129 * 4) : (2 * 128 * 64 * 2);
    __shared__ __attribute__((aligned(16))) char smem[SMEMB];
    __bf16* As = (__bf16*)smem;
    __bf16* Bs = As + 128 * 64;
    int t = threadIdx.x, w = t >> 6, l = t & 63;
    int r0 = blockIdx.y * 128, c0 = blockIdx.x * 128;
    int lr = l & 15, lg = l >> 4;
    int wr = (w >> 1) * 64, wc = (w & 1) * 64;
    f32x4 acc[4][4] = {};
    for (int k0 = 0; k0 < K; k0 += 64) {
        const __bf16* Ab = A0;
        int kk = k0;
        size_t KA = CONCAT ? 512 : (size_t)K;
        if (CONCAT && k0 >= 512) { Ab = A1; kk = k0 - 512; }
        #pragma unroll
        for (int i = 0; i < 4; ++i) {
            int row = (w * 4 + i) * 8 + (l >> 3);
            int c8 = l & 7;
            gload_lds16(Ab + (size_t)(r0 + row) * KA + kk + c8 * 8,
                        As + (w * 4 + i) * 512);
            gload_lds16(WT + (size_t)(c0 + row) * K + k0 + c8 * 8,
                        Bs + (w * 4 + i) * 512);
        }
        asm volatile("s_waitcnt vmcnt(0)" ::: "memory");
        __syncthreads();
        #pragma unroll
        for (int ks = 0; ks < 2; ++ks) {
            bf16x8 af[4], bfr[4];
            #pragma unroll
            for (int mi = 0; mi < 4; ++mi)
                af[mi] = *(const bf16x8*)(As + (wr + mi * 16 + lr) * 64 + ks * 32 + lg * 8);
            #pragma unroll
            for (int ni = 0; ni < 4; ++ni)
                bfr[ni] = *(const bf16x8*)(Bs + (wc + ni * 16 + lr) * 64 + ks * 32 + lg * 8);
            #pragma unroll
            for (int mi = 0; mi < 4; ++mi)
                #pragma unroll
                for (int ni = 0; ni < 4; ++ni)
                    acc[mi][ni] = __builtin_amdgcn_mfma_f32_16x16x32_bf16(
                        af[mi], bfr[ni], acc[mi][ni], 0, 0, 0);
        }
        __syncthreads();
    }
    if constexpr ((FLAGS & 8) != 0) {
        // transposed epilogue: stage 128x128 f32 tile in LDS, write out[b][c][i]
        float* tile = (float*)smem;
        #pragma unroll
        for (int mi = 0; mi < 4; ++mi)
            #pragma unroll
            for (int r = 0; r < 4; ++r) {
                int rrow = wr + mi * 16 + lg * 4 + r;
                #pragma unroll
                for (int ni = 0; ni < 4; ++ni) {
                    int ccol = wc + ni * 16 + lr;
                    float v = acc[mi][ni][r] + bias[c0 + ccol];
                    if constexpr ((FLAGS & 1) != 0) v = fmaxf(v, 0.f);
                    tile[rrow * 129 + ccol] = v;
                }
            }
        __syncthreads();
        int cc = t >> 6, rr2 = t & 63;
        #pragma unroll
        for (int cs = 0; cs < 128; cs += 4) {
            #pragma unroll
            for (int h = 0; h < 2; ++h) {
                int row = r0 + rr2 + h * 64;
                int bb = row / NPT, ii = row - bb * NPT;
                Cf[((size_t)bb * 512 + (c0 + cc + cs)) * NPT + ii] =
                    tile[(rr2 + h * 64) * 129 + cc + cs];
            }
        }
    } else {
        #pragma unroll
        for (int mi = 0; mi < 4; ++mi) {
            #pragma unroll
            for (int r = 0; r < 4; ++r) {
                int row = r0 + wr + mi * 16 + lg * 4 + r;
                float dsc = 1.f;
                if constexpr ((FLAGS & 2) != 0) {
                    int dr = row;
                    if (dr >= ROWS) dr -= ROWS;
                    dsc = degf[dr];
                }
                #pragma unroll
                for (int ni = 0; ni < 4; ++ni) {
                    int col = c0 + wc + ni * 16 + lr;
                    float v = acc[mi][ni][r] + dsc * bias[col];
                    if constexpr ((FLAGS & 1) != 0) v = fmaxf(v, 0.f);
                    if constexpr ((FLAGS & 4) != 0)
                        Cb[(size_t)row * N + col] = (__bf16)v;
                    else
                        Cf[(size_t)row * N + col] = v;
                }
            }
        }
    }
}

// ---------------- all weight transposes (f32->bf16, [K][N]->[N][K]) in one dispatch ----------------
__global__ __launch_bounds__(256) void transpose_all(
        const float* __restrict__ fc1_w, const float* __restrict__ fc2_w,
        const float* __restrict__ fce_w, const float* __restrict__ inout_w,
        const float* __restrict__ upd_w,
        __bf16* __restrict__ fc1t, __bf16* __restrict__ fc2t,
        __bf16* __restrict__ fcet, __bf16* __restrict__ inoutT,
        __bf16* __restrict__ updT) {
    __shared__ float tile[64][65];
    int bid = blockIdx.x;
    const float* W; __bf16* WT; int K, N, local;
    if (bid < 32)       { W = fc1_w;   WT = fc1t;   K = 512;  N = 256; local = bid; }
    else if (bid < 64)  { W = fc2_w;   WT = fc2t;   K = 512;  N = 256; local = bid - 32; }
    else if (bid < 96)  { W = fce_w;   WT = fcet;   K = 256;  N = 512; local = bid - 64; }
    else if (bid < 128) { W = inout_w; WT = inoutT; K = 256;  N = 512; local = bid - 96; }
    else                { W = upd_w;   WT = updT;   K = 1024; N = 512; local = bid - 128; }
    int ny = N >> 6;
    int k0 = (local / ny) * 64, n0 = (local % ny) * 64;
    int t = threadIdx.x;
    #pragma unroll
    for (int s = 0; s < 16; ++s) {
        int idx = s * 256 + t;
        int kk = idx >> 6, nn = idx & 63;
        tile[kk][nn] = W[(size_t)(k0 + kk) * N + n0 + nn];
    }
    __syncthreads();
    #pragma unroll
    for (int s = 0; s < 16; ++s) {
        int idx = s * 256 + t;
        int nn = idx >> 6, kk = idx & 63;
        WT[(size_t)(n0 + nn) * K + k0 + kk] = (__bf16)tile[kk][nn];
    }
}

// ---------------- flat f32 -> bf16 ----------------
__global__ __launch_bounds__(256) void convert_bf16(const float* __restrict__ src,
                                                    __bf16* __restrict__ dst) {
    int idx = blockIdx.x * 256 + threadIdx.x;
    float4 v = *(const float4*)(src + (size_t)idx * 4);
    bf16x4 o;
    o[0] = (__bf16)v.x; o[1] = (__bf16)v.y; o[2] = (__bf16)v.z; o[3] = (__bf16)v.w;
    *(bf16x4*)(dst + (size_t)idx * 4) = o;
}

// ---------------- fused mix ----------------
__global__ __launch_bounds__(256) void fuse_mix(const float* __restrict__ XA,
        const float* __restrict__ YA, const float* __restrict__ wgt,
        __bf16* __restrict__ F) {
    int idx = blockIdx.x * 256 + threadIdx.x;
    size_t e0 = (size_t)idx * 4;
    int r = (int)(e0 >> 9);
    float wv = wgt[r];
    float4 xv = *(const float4*)(XA + e0);
    float4 yv = *(const float4*)(YA + e0);
    bf16x4 o;
    o[0] = (__bf16)(wv * xv.x + (1.f - wv) * yv.x);
    o[1] = (__bf16)(wv * xv.y + (1.f - wv) * yv.y);
    o[2] = (__bf16)(wv * xv.z + (1.f - wv) * yv.z);
    o[3] = (__bf16)(wv * xv.w + (1.f - wv) * yv.w);
    *(bf16x4*)(F + e0) = o;
}

// ---------------- attention scores ----------------
__global__ __launch_bounds__(256) void scores_kernel(const float* __restrict__ xagg,
        const float* __restrict__ yagg, const float* __restrict__ aw,
        const float* __restrict__ ab, float* __restrict__ scores) {
    int g = threadIdx.x >> 6, lane = threadIdx.x & 63;
    int r = blockIdx.x * 4 + g;
    float acc = 0.f;
    #pragma unroll
    for (int s = 0; s < 8; ++s) {
        int c = lane + 64 * s;
        acc = fmaf(xagg[(size_t)r * 512 + c], aw[c], acc);
        acc = fmaf(yagg[(size_t)r * 512 + c], aw[512 + c], acc);
    }
    #pragma unroll
    for (int off = 32; off; off >>= 1) acc += __shfl_xor(acc, off, 64);
    if (lane == 0) scores[r] = acc + ab[0];
}

// ---------------- global softmax ----------------
__global__ __launch_bounds__(1024) void softmax_kernel(const float* __restrict__ scores,
                                                       float* __restrict__ wgt) {
    __shared__ float red[1024];
    int t = threadIdx.x;
    float mx = -3.402823466e+38f;
    for (int i = t; i < ROWS; i += 1024) mx = fmaxf(mx, scores[i]);
    red[t] = mx; __syncthreads();
    for (int off = 512; off; off >>= 1) {
        if (t < off) red[t] = fmaxf(red[t], red[t + off]);
        __syncthreads();
    }
    mx = red[0]; __syncthreads();
    float sm = 0.f;
    for (int i = t; i < ROWS; i += 1024) sm += expf(scores[i] - mx);
    red[t] = sm; __syncthreads();
    for (int off = 512; off; off >>= 1) {
        if (t < off) red[t] += red[t + off];
        __syncthreads();
    }
    float denom = red[0];
    for (int i = t; i < ROWS; i += 1024) wgt[i] = expf(scores[i] - mx) / denom;
}

extern "C" void kernel_launch(void* const* d_in, const int* in_sizes, int n_in,
                              void* d_out, int out_size, void* d_ws, size_t ws_size,
                              hipStream_t stream) {
    (void)in_sizes; (void)n_in; (void)out_size; (void)ws_size;
    const float* x       = (const float*)d_in[0];
    const float* fc1_w   = (const float*)d_in[1];
    const float* fc1_b   = (const float*)d_in[2];
    const float* fc2_w   = (const float*)d_in[3];
    const float* fc2_b   = (const float*)d_in[4];
    const float* fce_w   = (const float*)d_in[5];
    const float* fce_b   = (const float*)d_in[6];
    const float* inout_w = (const float*)d_in[7];
    const float* inout_b = (const float*)d_in[8];
    const float* attn_w  = (const float*)d_in[9];
    const float* attn_b  = (const float*)d_in[10];
    const float* upd_w   = (const float*)d_in[11];
    const float* upd_b   = (const float*)d_in[12];
    const float* kp_w    = (const float*)d_in[13];
    const float* kp_b    = (const float*)d_in[14];
    const float* enc_w   = (const float*)d_in[15];
    const float* enc_b   = (const float*)d_in[16];
    const float* mu_w    = (const float*)d_in[17];
    const float* mu_b    = (const float*)d_in[18];
    const float* dec_w   = (const float*)d_in[19];
    const float* dec_b   = (const float*)d_in[20];
    float* out = (float*)d_out;

    char* base = (char*)d_ws;
    size_t o = 0;
    auto alloc = [&](size_t bytes) -> void* {
        void* p = base + o;
        o += (bytes + 255) & ~(size_t)255;
        return p;
    };
    float* qs     = (float*)alloc(ROWS * 4);
    float* degf   = (float*)alloc(ROWS * 4);
    float* scores = (float*)alloc(ROWS * 4);
    float* wgt    = (float*)alloc(ROWS * 4);
    int*   kint   = (int*)  alloc(ROWS * 4);
    float* W1     = (float*)alloc(256 * 64 * 4);
    float* b1     = (float*)alloc(64 * 4);
    float* W2     = (float*)alloc(64 * 9 * 4);
    float* b2     = (float*)alloc(9 * 4);
    float* D      = (float*)alloc((size_t)128 * NPT * NPT * 4);   // 19.66 MB
    int*   nbr    = (int*)  alloc((size_t)128 * NPT * KNB * 4);   //  0.80 MB
    __bf16* Z     = (__bf16*)alloc((size_t)2 * ROWS * 512 * 2);   // 25.69 MB
    __bf16* H1    = (__bf16*)alloc((size_t)2 * ROWS * 256 * 2);   // 12.85 MB
    __bf16* XB    = (__bf16*)alloc((size_t)ROWS * 256 * 2);       //  6.42 MB
    float* AGG    = (float*)alloc((size_t)2 * ROWS * 512 * 4);    // 51.38 MB
    __bf16* fc1t  = (__bf16*)alloc((size_t)512 * 256 * 2);
    __bf16* fc2t  = (__bf16*)alloc((size_t)512 * 256 * 2);
    __bf16* fcet  = (__bf16*)alloc((size_t)256 * 512 * 2);
    __bf16* inoutT= (__bf16*)alloc((size_t)256 * 512 * 2);
    __bf16* updT  = (__bf16*)alloc((size_t)1024 * 512 * 2);
    // aliases (stream-ordered safe):
    __bf16* H2    = (__bf16*)D;                    // H2 (12.85MB) over D: D dead after topk
    __bf16* FUSED = Z;                             // FUSED over Z 1st half: Z dead after fc2
    __bf16* XIN   = Z + (size_t)ROWS * 512;        // XIN over Z 2nd half
    _Float16* XSPH = (_Float16*)AGG;               // XSPH/XSPL over AGG: dead before fce
    _Float16* XSPL = XSPH + (size_t)64 * 256 * 256;
    float* XAGG   = AGG;
    float* YAGG   = AGG + (size_t)ROWS * 512;

    // ---- prep: weights + composed k-predictor + x conversions ----
    transpose_all<<<256, 256, 0, stream>>>(fc1_w, fc2_w, fce_w, inout_w, upd_w,
                                           fc1t, fc2t, fcet, inoutT, updT);
    compose_all<<<68, 256, 0, stream>>>(kp_w, kp_b, enc_w, enc_b,
                                        mu_w, mu_b, dec_w, dec_b, W1, b1, W2, b2);
    convert_bf16<<<3136, 256, 0, stream>>>(x, XB);
    qs_kernel<<<64, 256, 0, stream>>>(x, qs);
    trans_split<<<dim3(4, 4, 64), 256, 0, stream>>>(x, XSPH, XSPL);

    // ---- KNN + k-predictor ----
    gram_mfma<<<dim3(2, 2, 128), 256, 0, stream>>>(XSPH, XSPL, D);
    topk_kernel<<<(128 * NPT) / 4, 256, 0, stream>>>(D, qs, nbr);
    kint2_kernel<<<ROWS / 16, 256, 0, stream>>>(x, W1, b1, W2, b2, kint, degf);

    // ---- merged x+y branches ----
    gatherS1<<<2 * ROWS / 4, 256, 0, stream>>>(x, nbr, kint, degf, Z);
    mfma_gemm<7, 0><<<dim3(2, 196), 256, 0, stream>>>(
        Z, nullptr, fc1t, fc1_b, degf, nullptr, H1, 512, 256);
    gatherS2<<<2 * ROWS / 4, 256, 0, stream>>>(H1, nbr, kint, degf, Z);
    mfma_gemm<6, 0><<<dim3(2, 196), 256, 0, stream>>>(
        Z, nullptr, fc2t, fc2_b, degf, nullptr, H2, 512, 256);
    mfma_gemm<0, 0><<<dim3(4, 196), 256, 0, stream>>>(
        H2, nullptr, fcet, fce_b, nullptr, AGG, nullptr, 256, 512);

    // ---- attention fusion ----
    scores_kernel<<<ROWS / 4, 256, 0, stream>>>(XAGG, YAGG, attn_w, attn_b, scores);
    softmax_kernel<<<1, 1024, 0, stream>>>(scores, wgt);
    fuse_mix<<<6272, 256, 0, stream>>>(XAGG, YAGG, wgt, FUSED);

    // ---- xin + final update GEMM (transposed epilogue writes out directly) ----
    mfma_gemm<4, 0><<<dim3(4, 98), 256, 0, stream>>>(
        XB, nullptr, inoutT, inout_b, nullptr, nullptr, XIN, 256, 512);
    mfma_gemm<9, 1><<<dim3(4, 98), 256, 0, stream>>>(
        XIN, FUSED, updT, upd_b, nullptr, out, nullptr, 1024, 512);
}